// Round 1
// baseline (1867.697 us; speedup 1.0000x reference)
//
#include <hip/hip_runtime.h>
#include <hip/hip_bf16.h>
#include <math.h>

#define BATCH 8192

// ---------------------------------------------------------------------------
// Kernel 1: fused conv1+bn+relu -> conv2+bn+relu -> conv3+bn+relu -> avgpool4
// One block (256 threads) per sample. LDS: bufA (x 64x64, later h2 16x16x16),
// h1s (8x32x32). 48 KB total -> 3 blocks/CU.
// ---------------------------------------------------------------------------
__global__ __launch_bounds__(256) void fused_cnn_kernel(
    const float* __restrict__ x,
    const float* __restrict__ c1w, const float* __restrict__ c1b,
    const float* __restrict__ bn1g, const float* __restrict__ bn1b,
    const float* __restrict__ bn1m, const float* __restrict__ bn1v,
    const float* __restrict__ c2w, const float* __restrict__ c2b,
    const float* __restrict__ bn2g, const float* __restrict__ bn2b,
    const float* __restrict__ bn2m, const float* __restrict__ bn2v,
    const float* __restrict__ c3w, const float* __restrict__ c3b,
    const float* __restrict__ bn3g, const float* __restrict__ bn3b,
    const float* __restrict__ bn3m, const float* __restrict__ bn3v,
    float* __restrict__ pooled)
{
    __shared__ float bufA[4096];   // x (64*64) then h2 (16*16*16)
    __shared__ float h1s[8192];    // 8*32*32

    const int tid = threadIdx.x;
    const int n = blockIdx.x;

    // ---- stage x[n] into LDS (coalesced float4) ----
    {
        const float4* xv = (const float4*)(x + (size_t)n * 4096);
        float4* bv = (float4*)bufA;
        #pragma unroll
        for (int i = 0; i < 4; ++i) bv[tid + 256 * i] = xv[tid + 256 * i];
    }
    __syncthreads();

    // ---- conv1: 1->8 ch, 5x5, stride 2, pad 2; out 8x32x32 ----
    #pragma unroll 4
    for (int i = 0; i < 32; ++i) {
        int o = tid + 256 * i;
        int c = o >> 10, rem = o & 1023, oy = rem >> 5, ox = rem & 31;
        int iy0 = 2 * oy - 2, ix0 = 2 * ox - 2;
        float acc = 0.f;
        #pragma unroll
        for (int ky = 0; ky < 5; ++ky) {
            int iy = iy0 + ky;
            if ((unsigned)iy >= 64u) continue;
            #pragma unroll
            for (int kx = 0; kx < 5; ++kx) {
                int ix = ix0 + kx;
                if ((unsigned)ix >= 64u) continue;
                acc = fmaf(bufA[iy * 64 + ix], c1w[c * 25 + ky * 5 + kx], acc);
            }
        }
        float s = bn1g[c] * rsqrtf(bn1v[c] + 1e-5f);
        float y = (acc + c1b[c] - bn1m[c]) * s + bn1b[c];
        h1s[o] = fmaxf(y, 0.f);
    }
    __syncthreads();

    // ---- conv2: 8->16 ch, 3x3, stride 2, pad 1; out 16x16x16 (into bufA) ----
    #pragma unroll 2
    for (int i = 0; i < 16; ++i) {
        int o = tid + 256 * i;
        int c = o >> 8, rem = o & 255, oy = rem >> 4, ox = rem & 15;
        int iy0 = 2 * oy - 1, ix0 = 2 * ox - 1;
        float acc = 0.f;
        for (int ic = 0; ic < 8; ++ic) {
            const float* wp = c2w + (c * 8 + ic) * 9;
            const float* hp = h1s + ic * 1024;
            #pragma unroll
            for (int ky = 0; ky < 3; ++ky) {
                int iy = iy0 + ky;
                if ((unsigned)iy >= 32u) continue;
                #pragma unroll
                for (int kx = 0; kx < 3; ++kx) {
                    int ix = ix0 + kx;
                    if ((unsigned)ix >= 32u) continue;
                    acc = fmaf(hp[iy * 32 + ix], wp[ky * 3 + kx], acc);
                }
            }
        }
        float s = bn2g[c] * rsqrtf(bn2v[c] + 1e-5f);
        float y = (acc + c2b[c] - bn2m[c]) * s + bn2b[c];
        bufA[o] = fmaxf(y, 0.f);   // safe: all reads of x finished at prior barrier
    }
    __syncthreads();

    // ---- conv3: 16->32 ch, 3x3, stride 1, pad 1; out 32x16x16 + bn/relu + 4x4 avgpool ----
    #pragma unroll
    for (int i = 0; i < 2; ++i) {
        int p = tid + 256 * i;          // pooled index: c*16 + ph*4 + pw
        int c = p >> 4, pos = p & 15, ph = pos >> 2, pw = pos & 3;
        float acc[16];
        #pragma unroll
        for (int t = 0; t < 16; ++t) acc[t] = 0.f;
        for (int ic = 0; ic < 16; ++ic) {
            float w[9];
            #pragma unroll
            for (int t = 0; t < 9; ++t) w[t] = c3w[(c * 16 + ic) * 9 + t];
            const float* hp = bufA + ic * 256;
            #pragma unroll
            for (int dy = 0; dy < 4; ++dy) {
                int oy = ph * 4 + dy;
                #pragma unroll
                for (int dx = 0; dx < 4; ++dx) {
                    int ox = pw * 4 + dx;
                    float a = acc[dy * 4 + dx];
                    #pragma unroll
                    for (int ky = 0; ky < 3; ++ky) {
                        int iy = oy + ky - 1;
                        if ((unsigned)iy >= 16u) continue;
                        #pragma unroll
                        for (int kx = 0; kx < 3; ++kx) {
                            int ix = ox + kx - 1;
                            if ((unsigned)ix >= 16u) continue;
                            a = fmaf(hp[iy * 16 + ix], w[ky * 3 + kx], a);
                        }
                    }
                    acc[dy * 4 + dx] = a;
                }
            }
        }
        float s = bn3g[c] * rsqrtf(bn3v[c] + 1e-5f);
        float sh = (c3b[c] - bn3m[c]) * s + bn3b[c];
        float sum = 0.f;
        #pragma unroll
        for (int t = 0; t < 16; ++t) sum += fmaxf(fmaf(acc[t], s, sh), 0.f);
        pooled[(size_t)n * 512 + p] = sum * (1.f / 16.f);
    }
}

// ---------------------------------------------------------------------------
// Kernel 2/3: tiled f32 GEMM  out[M,N] = relu(A[M,K] @ W[N,K]^T + bias)
// 64x64 tile, BK=16, 256 threads, 4x4 micro-tile per thread.
// ---------------------------------------------------------------------------
template <int RELU>
__global__ __launch_bounds__(256) void fc_kernel(
    const float* __restrict__ A, const float* __restrict__ W,
    const float* __restrict__ bias, float* __restrict__ out,
    int M, int N, int K)
{
    __shared__ float As[16][64];
    __shared__ float Ws[16][64];
    const int tid = threadIdx.x;
    const int bm = blockIdx.x * 64;
    const int bn = blockIdx.y * 64;
    const int tn = tid & 15, tm = tid >> 4;
    const int lr = tid >> 2;            // 0..63 tile row
    const int lc = (tid & 3) << 2;      // 0,4,8,12 k-offset

    float acc[4][4];
    #pragma unroll
    for (int i = 0; i < 4; ++i)
        #pragma unroll
        for (int j = 0; j < 4; ++j) acc[i][j] = 0.f;

    for (int k0 = 0; k0 < K; k0 += 16) {
        float4 av = *(const float4*)(A + (size_t)(bm + lr) * K + k0 + lc);
        float4 wv = *(const float4*)(W + (size_t)(bn + lr) * K + k0 + lc);
        As[lc + 0][lr] = av.x; As[lc + 1][lr] = av.y;
        As[lc + 2][lr] = av.z; As[lc + 3][lr] = av.w;
        Ws[lc + 0][lr] = wv.x; Ws[lc + 1][lr] = wv.y;
        Ws[lc + 2][lr] = wv.z; Ws[lc + 3][lr] = wv.w;
        __syncthreads();
        #pragma unroll
        for (int kk = 0; kk < 16; ++kk) {
            float4 a = *(const float4*)&As[kk][tm * 4];
            float4 w = *(const float4*)&Ws[kk][tn * 4];
            acc[0][0] = fmaf(a.x, w.x, acc[0][0]); acc[0][1] = fmaf(a.x, w.y, acc[0][1]);
            acc[0][2] = fmaf(a.x, w.z, acc[0][2]); acc[0][3] = fmaf(a.x, w.w, acc[0][3]);
            acc[1][0] = fmaf(a.y, w.x, acc[1][0]); acc[1][1] = fmaf(a.y, w.y, acc[1][1]);
            acc[1][2] = fmaf(a.y, w.z, acc[1][2]); acc[1][3] = fmaf(a.y, w.w, acc[1][3]);
            acc[2][0] = fmaf(a.z, w.x, acc[2][0]); acc[2][1] = fmaf(a.z, w.y, acc[2][1]);
            acc[2][2] = fmaf(a.z, w.z, acc[2][2]); acc[2][3] = fmaf(a.z, w.w, acc[2][3]);
            acc[3][0] = fmaf(a.w, w.x, acc[3][0]); acc[3][1] = fmaf(a.w, w.y, acc[3][1]);
            acc[3][2] = fmaf(a.w, w.z, acc[3][2]); acc[3][3] = fmaf(a.w, w.w, acc[3][3]);
        }
        __syncthreads();
    }

    #pragma unroll
    for (int i = 0; i < 4; ++i) {
        int row = bm + tm * 4 + i;
        float4 v;
        float* vp = (float*)&v;
        #pragma unroll
        for (int j = 0; j < 4; ++j) {
            float r = acc[i][j] + bias[bn + tn * 4 + j];
            if (RELU) r = fmaxf(r, 0.f);
            vp[j] = r;
        }
        *(float4*)(out + (size_t)row * N + bn + tn * 4) = v;
    }
}

// ---------------------------------------------------------------------------
// Kernel 4: L2-normalize + 8-qubit / 7-layer quantum sim -> <Z_0>
// One wave (64 lanes) per sample; 4 amplitudes per lane.
// Global amp index g = lane*4 + i. Wire q (PennyLane MSB-first): g bit (7-q).
// -> wires 0..5 live in lane bits 5..0; wires 6,7 live in register index i.
// ---------------------------------------------------------------------------
__global__ __launch_bounds__(256) void qsim_kernel(
    const float* __restrict__ feats, const float* __restrict__ qw,
    float* __restrict__ qout)
{
    const int lane = threadIdx.x & 63;
    const int wid = threadIdx.x >> 6;
    const int s = blockIdx.x * 4 + wid;

    float4 v = *(const float4*)(feats + (size_t)s * 256 + lane * 4);
    float a0 = v.x, a1 = v.y, a2 = v.z, a3 = v.w;

    // L2 norm across the wave
    float ss = a0 * a0 + a1 * a1 + a2 * a2 + a3 * a3;
    #pragma unroll
    for (int m = 32; m; m >>= 1) ss += __shfl_xor(ss, m);
    float inv = 1.f / fmaxf(sqrtf(ss), 1e-12f);
    a0 *= inv; a1 *= inv; a2 *= inv; a3 *= inv;

    for (int l = 0; l < 7; ++l) {
        // RY on wires 0..5 (lane-bit wires)
        #pragma unroll
        for (int q = 0; q < 6; ++q) {
            float th = 0.5f * qw[l * 8 + q];
            float sn, cs; __sincosf(th, &sn, &cs);   // fast approx; refine below if needed
            sn = sinf(th); cs = cosf(th);            // precise versions (uniform scalar work)
            int mask = 32 >> q;
            float sg = (lane & mask) ? sn : -sn;
            float b0 = __shfl_xor(a0, mask), b1 = __shfl_xor(a1, mask);
            float b2 = __shfl_xor(a2, mask), b3 = __shfl_xor(a3, mask);
            a0 = fmaf(sg, b0, cs * a0); a1 = fmaf(sg, b1, cs * a1);
            a2 = fmaf(sg, b2, cs * a2); a3 = fmaf(sg, b3, cs * a3);
        }
        // RY wire 6: pairs (i, i^2)
        {
            float th = 0.5f * qw[l * 8 + 6];
            float sn = sinf(th), cs = cosf(th);
            float n0 = cs * a0 - sn * a2, n2 = fmaf(sn, a0, cs * a2);
            float n1 = cs * a1 - sn * a3, n3 = fmaf(sn, a1, cs * a3);
            a0 = n0; a1 = n1; a2 = n2; a3 = n3;
        }
        // RY wire 7: pairs (i, i^1)
        {
            float th = 0.5f * qw[l * 8 + 7];
            float sn = sinf(th), cs = cosf(th);
            float n0 = cs * a0 - sn * a1, n1 = fmaf(sn, a0, cs * a1);
            float n2 = cs * a2 - sn * a3, n3 = fmaf(sn, a2, cs * a3);
            a0 = n0; a1 = n1; a2 = n2; a3 = n3;
        }
        // CNOT(q, q+1), q = 0..4: control & target both in lane bits
        #pragma unroll
        for (int q = 0; q < 5; ++q) {
            int cmask = 32 >> q, tmask = 16 >> q;
            int src = (lane & cmask) ? (lane ^ tmask) : lane;
            a0 = __shfl(a0, src); a1 = __shfl(a1, src);
            a2 = __shfl(a2, src); a3 = __shfl(a3, src);
        }
        // CNOT(5,6): control lane bit0, target i-bit1 -> swap (0,2),(1,3) where lane&1
        {
            bool f = (lane & 1);
            float n0 = f ? a2 : a0, n2 = f ? a0 : a2;
            float n1 = f ? a3 : a1, n3 = f ? a1 : a3;
            a0 = n0; a1 = n1; a2 = n2; a3 = n3;
        }
        // CNOT(6,7): control i-bit1, target i-bit0 -> swap a2<->a3
        { float t = a2; a2 = a3; a3 = t; }
    }

    // <Z_0>: wire0 = lane bit 5
    float part = a0 * a0 + a1 * a1 + a2 * a2 + a3 * a3;
    part = (lane & 32) ? -part : part;
    #pragma unroll
    for (int m = 32; m; m >>= 1) part += __shfl_xor(part, m);
    if (lane == 0) qout[s] = part;
}

// ---------------------------------------------------------------------------
// Kernel 5: tail MLP per sample: 1->64 (relu,BN) ->32 (relu) ->16 (relu) ->1 sigmoid
// ---------------------------------------------------------------------------
__global__ __launch_bounds__(256) void tail_kernel(
    const float* __restrict__ qv,
    const float* __restrict__ w1, const float* __restrict__ b1,
    const float* __restrict__ cg, const float* __restrict__ cb,
    const float* __restrict__ cm, const float* __restrict__ cv,
    const float* __restrict__ w2, const float* __restrict__ b2,
    const float* __restrict__ w3, const float* __restrict__ b3,
    const float* __restrict__ w4, const float* __restrict__ b4,
    float* __restrict__ out)
{
    const int s = blockIdx.x * 256 + threadIdx.x;
    float q = qv[s];

    float acc2[32];
    #pragma unroll
    for (int j = 0; j < 32; ++j) acc2[j] = b2[j];
    for (int i = 0; i < 64; ++i) {
        float z = fmaxf(fmaf(q, w1[i], b1[i]), 0.f);
        z = fmaf(z - cm[i], cg[i] * rsqrtf(cv[i] + 1e-5f), cb[i]);
        #pragma unroll
        for (int j = 0; j < 32; ++j) acc2[j] = fmaf(w2[j * 64 + i], z, acc2[j]);
    }
    float z3[16];
    #pragma unroll
    for (int j = 0; j < 16; ++j) {
        float a = b3[j];
        #pragma unroll
        for (int i = 0; i < 32; ++i) a = fmaf(w3[j * 32 + i], fmaxf(acc2[i], 0.f), a);
        z3[j] = fmaxf(a, 0.f);
    }
    float o = b4[0];
    #pragma unroll
    for (int i = 0; i < 16; ++i) o = fmaf(w4[i], z3[i], o);
    out[s] = 1.f / (1.f + expf(-o));
}

// ---------------------------------------------------------------------------
extern "C" void kernel_launch(void* const* d_in, const int* in_sizes, int n_in,
                              void* d_out, int out_size, void* d_ws, size_t ws_size,
                              hipStream_t stream)
{
    const float* x    = (const float*)d_in[0];
    const float* c1w  = (const float*)d_in[1];
    const float* c1b  = (const float*)d_in[2];
    const float* bn1g = (const float*)d_in[3];
    const float* bn1b = (const float*)d_in[4];
    const float* bn1m = (const float*)d_in[5];
    const float* bn1v = (const float*)d_in[6];
    const float* c2w  = (const float*)d_in[7];
    const float* c2b  = (const float*)d_in[8];
    const float* bn2g = (const float*)d_in[9];
    const float* bn2b = (const float*)d_in[10];
    const float* bn2m = (const float*)d_in[11];
    const float* bn2v = (const float*)d_in[12];
    const float* c3w  = (const float*)d_in[13];
    const float* c3b  = (const float*)d_in[14];
    const float* bn3g = (const float*)d_in[15];
    const float* bn3b = (const float*)d_in[16];
    const float* bn3m = (const float*)d_in[17];
    const float* bn3v = (const float*)d_in[18];
    const float* f1w  = (const float*)d_in[19];
    const float* f1b  = (const float*)d_in[20];
    const float* f2w  = (const float*)d_in[21];
    const float* f2b  = (const float*)d_in[22];
    const float* qw   = (const float*)d_in[23];
    const float* w1   = (const float*)d_in[24];
    const float* b1   = (const float*)d_in[25];
    const float* cg   = (const float*)d_in[26];
    const float* cb   = (const float*)d_in[27];
    const float* cm   = (const float*)d_in[28];
    const float* cv   = (const float*)d_in[29];
    const float* w2   = (const float*)d_in[30];
    const float* b2   = (const float*)d_in[31];
    const float* w3   = (const float*)d_in[32];
    const float* b3   = (const float*)d_in[33];
    const float* w4   = (const float*)d_in[34];
    const float* b4   = (const float*)d_in[35];

    float* ws = (float*)d_ws;
    float* pooled = ws;                          // 8192*512
    float* a1     = ws + (size_t)BATCH * 512;    // 8192*384
    float* a2     = ws;                          // reuse pooled region (8192*256)
    float* qv     = a1 + (size_t)BATCH * 384;    // 8192

    fused_cnn_kernel<<<BATCH, 256, 0, stream>>>(
        x, c1w, c1b, bn1g, bn1b, bn1m, bn1v,
        c2w, c2b, bn2g, bn2b, bn2m, bn2v,
        c3w, c3b, bn3g, bn3b, bn3m, bn3v, pooled);

    dim3 g1(BATCH / 64, 384 / 64);
    fc_kernel<1><<<g1, 256, 0, stream>>>(pooled, f1w, f1b, a1, BATCH, 384, 512);

    dim3 g2(BATCH / 64, 256 / 64);
    fc_kernel<1><<<g2, 256, 0, stream>>>(a1, f2w, f2b, a2, BATCH, 256, 384);

    qsim_kernel<<<BATCH / 4, 256, 0, stream>>>(a2, qw, qv);

    tail_kernel<<<BATCH / 256, 256, 0, stream>>>(
        qv, w1, b1, cg, cb, cm, cv, w2, b2, w3, b3, w4, b4, (float*)d_out);
}

// Round 2
// 262.417 us; speedup vs baseline: 7.1173x; 7.1173x over previous
//
#include <hip/hip_runtime.h>
#include <hip/hip_bf16.h>
#include <math.h>

#define BATCH 8192

typedef __attribute__((ext_vector_type(8))) short bf16x8;
typedef __attribute__((ext_vector_type(4))) float f32x4;

__device__ __forceinline__ unsigned short f2bf(float f) {
    unsigned int u = __builtin_bit_cast(unsigned int, f);
    u = (u + 0x7FFFu + ((u >> 16) & 1u)) >> 16;
    return (unsigned short)u;
}
__device__ __forceinline__ float bf2f(unsigned short h) {
    unsigned int u = ((unsigned int)h) << 16;
    return __builtin_bit_cast(float, u);
}

// ---- packed weight-fragment layout in ws (ushorts) ----
// frag = 64 lanes x 8 bf16 = 512 ush. Lane l holds k=8*(l>>4)+j, col=l&15.
#define W1OFF 0
#define W1FRAGS 10                      // [ky=5][hl=2]
#define W2OFF (W1OFF + W1FRAGS * 512)
#define W2FRAGS 6                       // [ky=3][hl=2]
#define W3OFF (W2OFF + W2FRAGS * 512)
#define W3FRAGS 24                      // [ky=3][kxp=2][oct=2][hl=2]
#define WPACK_TOTAL (W3OFF + W3FRAGS * 512)   // 20480 ush = 40 KB

// ---------------------------------------------------------------------------
// Prepack conv weights into MFMA B-fragments, hi/lo bf16 split.
// conv1: K=32 k=kx (<5 valid), col=oc (<8 valid)
// conv2: K=32 k=(kx<<3)|ic (kx<3 valid), col=oc
// conv3: K=32 k=(pixoff<<4)|ic, kx=kxp*2+pixoff (<3 valid), col=oc&15 (+16*oct)
// ---------------------------------------------------------------------------
__global__ __launch_bounds__(256) void prepack_kernel(
    const float* __restrict__ c1w, const float* __restrict__ c2w,
    const float* __restrict__ c3w, unsigned short* __restrict__ wpack)
{
    int e = blockIdx.x * 256 + threadIdx.x;
    if (e >= WPACK_TOTAL) return;
    int f = e >> 9;
    int r = e & 511;
    int l = r >> 3, j = r & 7;
    int k = 8 * (l >> 4) + j;
    int col = l & 15;
    float w = 0.f;
    int hl;
    if (e < W2OFF) {
        int ky = f >> 1; hl = f & 1;
        int kx = k;
        if (kx < 5 && col < 8) w = c1w[col * 25 + ky * 5 + kx];
    } else if (e < W3OFF) {
        int f2 = f - W1FRAGS;
        int ky = f2 >> 1; hl = f2 & 1;
        int kx = k >> 3, ic = k & 7;
        if (kx < 3) w = c2w[((col * 8 + ic) * 3 + ky) * 3 + kx];
    } else {
        int f3 = f - W1FRAGS - W2FRAGS;      // ((ky*2+kxp)*2+oct)*2+hl
        int ky = f3 >> 3, kxp = (f3 >> 2) & 1, oct = (f3 >> 1) & 1;
        hl = f3 & 1;
        int kx = kxp * 2 + (k >> 4), ic = k & 15, oc = col + 16 * oct;
        if (kx < 3) w = c3w[((oc * 16 + ic) * 3 + ky) * 3 + kx];
    }
    unsigned short hv = f2bf(w);
    unsigned short lv = f2bf(w - bf2f(hv));
    wpack[e] = hl ? lv : hv;
}

// ---------------------------------------------------------------------------
// Fused CNN: stage x->bf16 LDS -> conv1(MFMA) -> conv2(MFMA) -> conv3(MFMA)
// -> BN/ReLU -> 4x4 avgpool (in-register), one block (4 waves) per sample.
// LDS: h1p 34x34x8 bf16 (18496 B), sbuf = xp 68x68 bf16 / h2p 18x18x16 bf16.
// ---------------------------------------------------------------------------
__global__ __launch_bounds__(256) void fused_cnn_mfma(
    const float* __restrict__ x,
    const float* __restrict__ c1b,
    const float* __restrict__ bn1g, const float* __restrict__ bn1b,
    const float* __restrict__ bn1m, const float* __restrict__ bn1v,
    const float* __restrict__ c2b,
    const float* __restrict__ bn2g, const float* __restrict__ bn2b,
    const float* __restrict__ bn2m, const float* __restrict__ bn2v,
    const float* __restrict__ c3b,
    const float* __restrict__ bn3g, const float* __restrict__ bn3b,
    const float* __restrict__ bn3m, const float* __restrict__ bn3v,
    const unsigned short* __restrict__ wpack,
    float* __restrict__ pooled)
{
    __shared__ unsigned short h1p[9248];   // (34*34)*8
    __shared__ unsigned short sbuf[5200];  // max(68*68=4624, 18*18*16=5184)+slack

    const int tid = threadIdx.x;
    const int lane = tid & 63;
    const int wv = tid >> 6;          // wave 0..3
    const int n = blockIdx.x;
    const int lrow = lane & 15;
    const int lq = lane >> 4;         // 0..3

    // ---- phase 0: zero xp region + h1p (pads must be 0) ----
    {
        unsigned int* z1 = (unsigned int*)sbuf;
        for (int i = tid; i < 2600; i += 256) z1[i] = 0u;
        unsigned int* z2 = (unsigned int*)h1p;
        for (int i = tid; i < 4624; i += 256) z2[i] = 0u;
    }
    __syncthreads();

    // ---- stage x[n] -> xp bf16, pad 2 ----
    {
        const float4* xv = (const float4*)(x + (size_t)n * 4096);
        #pragma unroll
        for (int i = 0; i < 4; ++i) {
            int idx = tid + 256 * i;          // 1024 float4 total
            float4 v = xv[idx];
            int px = idx * 4;
            int y = px >> 6, xc = px & 63;
            int base = (y + 2) * 68 + xc + 2;  // even
            unsigned int p0 = (unsigned int)f2bf(v.x) | ((unsigned int)f2bf(v.y) << 16);
            unsigned int p1 = (unsigned int)f2bf(v.z) | ((unsigned int)f2bf(v.w) << 16);
            *(unsigned int*)&sbuf[base] = p0;
            *(unsigned int*)&sbuf[base + 2] = p1;
        }
    }
    __syncthreads();

    // ---- conv1: 1->8ch 5x5 s2 p2, out 8x32x32 -> h1p ----
    {
        bf16x8 w1f[5][2];
        #pragma unroll
        for (int ky = 0; ky < 5; ++ky)
            #pragma unroll
            for (int hl = 0; hl < 2; ++hl) {
                uint4 b = *(const uint4*)(wpack + W1OFF + (ky * 2 + hl) * 512 + lane * 8);
                w1f[ky][hl] = __builtin_bit_cast(bf16x8, b);
            }
        int oc = lrow;
        float s1 = 0.f, sh1 = 0.f;
        if (oc < 8) {
            s1 = bn1g[oc] * rsqrtf(bn1v[oc] + 1e-5f);
            sh1 = (c1b[oc] - bn1m[oc]) * s1 + bn1b[oc];
        }
        for (int t = 0; t < 16; ++t) {
            int m = wv * 16 + t;
            int oy = m >> 1, h = m & 1;        // global ox = 16h + row
            f32x4 acc = {0.f, 0.f, 0.f, 0.f};
            #pragma unroll
            for (int ky = 0; ky < 5; ++ky) {
                int iy = 2 * oy + ky;                          // padded row
                int base = iy * 68 + 2 * lrow + 32 * h + 8 * lq; // ush, even
                const unsigned int* p = (const unsigned int*)sbuf + (base >> 1);
                uint4 d; d.x = p[0]; d.y = p[1]; d.z = p[2]; d.w = p[3];
                bf16x8 a = __builtin_bit_cast(bf16x8, d);
                acc = __builtin_amdgcn_mfma_f32_16x16x32_bf16(a, w1f[ky][0], acc, 0, 0, 0);
                acc = __builtin_amdgcn_mfma_f32_16x16x32_bf16(a, w1f[ky][1], acc, 0, 0, 0);
            }
            if (oc < 8) {
                #pragma unroll
                for (int r = 0; r < 4; ++r) {
                    int ox = 16 * h + 4 * lq + r;
                    float yv = fmaxf(fmaf(acc[r], s1, sh1), 0.f);
                    h1p[((oy + 1) * 34 + ox + 1) * 8 + oc] = f2bf(yv);
                }
            }
        }
    }
    __syncthreads();

    // ---- zero h2p region (pads) ----
    {
        unsigned int* z = (unsigned int*)sbuf;
        for (int i = tid; i < 2600; i += 256) z[i] = 0u;
    }
    __syncthreads();

    // ---- conv2: 8->16ch 3x3 s2 p1, out 16x16x16 -> h2p ----
    {
        bf16x8 w2f[3][2];
        #pragma unroll
        for (int ky = 0; ky < 3; ++ky)
            #pragma unroll
            for (int hl = 0; hl < 2; ++hl) {
                uint4 b = *(const uint4*)(wpack + W2OFF + (ky * 2 + hl) * 512 + lane * 8);
                w2f[ky][hl] = __builtin_bit_cast(bf16x8, b);
            }
        int oc = lrow;
        float s2 = bn2g[oc] * rsqrtf(bn2v[oc] + 1e-5f);
        float sh2 = (c2b[oc] - bn2m[oc]) * s2 + bn2b[oc];
        #pragma unroll
        for (int t = 0; t < 4; ++t) {
            int oy = 4 * wv + t;
            f32x4 acc = {0.f, 0.f, 0.f, 0.f};
            #pragma unroll
            for (int ky = 0; ky < 3; ++ky) {
                int iy = 2 * oy + ky;                 // padded
                int pix = iy * 34 + 2 * lrow + lq;    // k>>3 = kx offset
                bf16x8 a = __builtin_bit_cast(bf16x8, *(const uint4*)(h1p + pix * 8));
                acc = __builtin_amdgcn_mfma_f32_16x16x32_bf16(a, w2f[ky][0], acc, 0, 0, 0);
                acc = __builtin_amdgcn_mfma_f32_16x16x32_bf16(a, w2f[ky][1], acc, 0, 0, 0);
            }
            #pragma unroll
            for (int r = 0; r < 4; ++r) {
                int ox = 4 * lq + r;
                float yv = fmaxf(fmaf(acc[r], s2, sh2), 0.f);
                sbuf[((oy + 1) * 18 + ox + 1) * 16 + oc] = f2bf(yv);
            }
        }
    }
    __syncthreads();

    // ---- conv3: 16->32ch 3x3 s1 p1 + BN/ReLU + 4x4 avgpool (in-register) ----
    {
        f32x4 ps[4][2];
        #pragma unroll
        for (int t = 0; t < 4; ++t)
            #pragma unroll
            for (int o = 0; o < 2; ++o) ps[t][o] = (f32x4){0.f, 0.f, 0.f, 0.f};

        #pragma unroll
        for (int ky = 0; ky < 3; ++ky)
            #pragma unroll
            for (int kxp = 0; kxp < 2; ++kxp) {
                int fb = (ky * 2 + kxp) * 4;     // [oct][hl]
                bf16x8 b00 = __builtin_bit_cast(bf16x8, *(const uint4*)(wpack + W3OFF + (fb + 0) * 512 + lane * 8));
                bf16x8 b01 = __builtin_bit_cast(bf16x8, *(const uint4*)(wpack + W3OFF + (fb + 1) * 512 + lane * 8));
                bf16x8 b10 = __builtin_bit_cast(bf16x8, *(const uint4*)(wpack + W3OFF + (fb + 2) * 512 + lane * 8));
                bf16x8 b11 = __builtin_bit_cast(bf16x8, *(const uint4*)(wpack + W3OFF + (fb + 3) * 512 + lane * 8));
                #pragma unroll
                for (int t = 0; t < 4; ++t) {
                    int oy = 4 * wv + t;
                    int iy = oy + ky;                          // padded
                    int pix = iy * 18 + lrow + 2 * kxp + (lq >> 1);
                    bf16x8 a = __builtin_bit_cast(bf16x8,
                        *(const uint4*)(sbuf + pix * 16 + (lq & 1) * 8));
                    ps[t][0] = __builtin_amdgcn_mfma_f32_16x16x32_bf16(a, b00, ps[t][0], 0, 0, 0);
                    ps[t][0] = __builtin_amdgcn_mfma_f32_16x16x32_bf16(a, b01, ps[t][0], 0, 0, 0);
                    ps[t][1] = __builtin_amdgcn_mfma_f32_16x16x32_bf16(a, b10, ps[t][1], 0, 0, 0);
                    ps[t][1] = __builtin_amdgcn_mfma_f32_16x16x32_bf16(a, b11, ps[t][1], 0, 0, 0);
                }
            }

        #pragma unroll
        for (int oct = 0; oct < 2; ++oct) {
            int oc = lrow + 16 * oct;
            float s3 = bn3g[oc] * rsqrtf(bn3v[oc] + 1e-5f);
            float sh3 = (c3b[oc] - bn3m[oc]) * s3 + bn3b[oc];
            float pool = 0.f;
            #pragma unroll
            for (int t = 0; t < 4; ++t)
                #pragma unroll
                for (int r = 0; r < 4; ++r)
                    pool += fmaxf(fmaf(ps[t][oct][r], s3, sh3), 0.f);
            pooled[(size_t)n * 512 + oc * 16 + wv * 4 + lq] = pool * (1.f / 16.f);
        }
    }
}

// ---------------------------------------------------------------------------
// FC GEMM: out[M,N] = relu(A[M,K] @ W[N,K]^T + bias). 64x64 tile, f32.
// ---------------------------------------------------------------------------
template <int RELU>
__global__ __launch_bounds__(256) void fc_kernel(
    const float* __restrict__ A, const float* __restrict__ W,
    const float* __restrict__ bias, float* __restrict__ out,
    int M, int N, int K)
{
    __shared__ float As[16][64];
    __shared__ float Ws[16][64];
    const int tid = threadIdx.x;
    const int bm = blockIdx.x * 64;
    const int bn = blockIdx.y * 64;
    const int tn = tid & 15, tm = tid >> 4;
    const int lr = tid >> 2;
    const int lc = (tid & 3) << 2;

    float acc[4][4];
    #pragma unroll
    for (int i = 0; i < 4; ++i)
        #pragma unroll
        for (int j = 0; j < 4; ++j) acc[i][j] = 0.f;

    for (int k0 = 0; k0 < K; k0 += 16) {
        float4 av = *(const float4*)(A + (size_t)(bm + lr) * K + k0 + lc);
        float4 wv = *(const float4*)(W + (size_t)(bn + lr) * K + k0 + lc);
        As[lc + 0][lr] = av.x; As[lc + 1][lr] = av.y;
        As[lc + 2][lr] = av.z; As[lc + 3][lr] = av.w;
        Ws[lc + 0][lr] = wv.x; Ws[lc + 1][lr] = wv.y;
        Ws[lc + 2][lr] = wv.z; Ws[lc + 3][lr] = wv.w;
        __syncthreads();
        #pragma unroll
        for (int kk = 0; kk < 16; ++kk) {
            float4 a = *(const float4*)&As[kk][tm * 4];
            float4 w = *(const float4*)&Ws[kk][tn * 4];
            acc[0][0] = fmaf(a.x, w.x, acc[0][0]); acc[0][1] = fmaf(a.x, w.y, acc[0][1]);
            acc[0][2] = fmaf(a.x, w.z, acc[0][2]); acc[0][3] = fmaf(a.x, w.w, acc[0][3]);
            acc[1][0] = fmaf(a.y, w.x, acc[1][0]); acc[1][1] = fmaf(a.y, w.y, acc[1][1]);
            acc[1][2] = fmaf(a.y, w.z, acc[1][2]); acc[1][3] = fmaf(a.y, w.w, acc[1][3]);
            acc[2][0] = fmaf(a.z, w.x, acc[2][0]); acc[2][1] = fmaf(a.z, w.y, acc[2][1]);
            acc[2][2] = fmaf(a.z, w.z, acc[2][2]); acc[2][3] = fmaf(a.z, w.w, acc[2][3]);
            acc[3][0] = fmaf(a.w, w.x, acc[3][0]); acc[3][1] = fmaf(a.w, w.y, acc[3][1]);
            acc[3][2] = fmaf(a.w, w.z, acc[3][2]); acc[3][3] = fmaf(a.w, w.w, acc[3][3]);
        }
        __syncthreads();
    }

    #pragma unroll
    for (int i = 0; i < 4; ++i) {
        int row = bm + tm * 4 + i;
        float4 v;
        float* vp = (float*)&v;
        #pragma unroll
        for (int j = 0; j < 4; ++j) {
            float r = acc[i][j] + bias[bn + tn * 4 + j];
            if (RELU) r = fmaxf(r, 0.f);
            vp[j] = r;
        }
        *(float4*)(out + (size_t)row * N + bn + tn * 4) = v;
    }
}

// ---------------------------------------------------------------------------
// L2-normalize + 8-qubit/7-layer qsim -> <Z_0>. One wave per sample.
// ---------------------------------------------------------------------------
__global__ __launch_bounds__(256) void qsim_kernel(
    const float* __restrict__ feats, const float* __restrict__ qw,
    float* __restrict__ qout)
{
    const int lane = threadIdx.x & 63;
    const int wid = threadIdx.x >> 6;
    const int s = blockIdx.x * 4 + wid;

    float4 v = *(const float4*)(feats + (size_t)s * 256 + lane * 4);
    float a0 = v.x, a1 = v.y, a2 = v.z, a3 = v.w;

    float ss = a0 * a0 + a1 * a1 + a2 * a2 + a3 * a3;
    #pragma unroll
    for (int m = 32; m; m >>= 1) ss += __shfl_xor(ss, m);
    float inv = 1.f / fmaxf(sqrtf(ss), 1e-12f);
    a0 *= inv; a1 *= inv; a2 *= inv; a3 *= inv;

    for (int l = 0; l < 7; ++l) {
        #pragma unroll
        for (int q = 0; q < 6; ++q) {
            float th = 0.5f * qw[l * 8 + q];
            float sn = sinf(th), cs = cosf(th);
            int mask = 32 >> q;
            float sg = (lane & mask) ? sn : -sn;
            float b0 = __shfl_xor(a0, mask), b1 = __shfl_xor(a1, mask);
            float b2 = __shfl_xor(a2, mask), b3 = __shfl_xor(a3, mask);
            a0 = fmaf(sg, b0, cs * a0); a1 = fmaf(sg, b1, cs * a1);
            a2 = fmaf(sg, b2, cs * a2); a3 = fmaf(sg, b3, cs * a3);
        }
        {
            float th = 0.5f * qw[l * 8 + 6];
            float sn = sinf(th), cs = cosf(th);
            float n0 = cs * a0 - sn * a2, n2 = fmaf(sn, a0, cs * a2);
            float n1 = cs * a1 - sn * a3, n3 = fmaf(sn, a1, cs * a3);
            a0 = n0; a1 = n1; a2 = n2; a3 = n3;
        }
        {
            float th = 0.5f * qw[l * 8 + 7];
            float sn = sinf(th), cs = cosf(th);
            float n0 = cs * a0 - sn * a1, n1 = fmaf(sn, a0, cs * a1);
            float n2 = cs * a2 - sn * a3, n3 = fmaf(sn, a2, cs * a3);
            a0 = n0; a1 = n1; a2 = n2; a3 = n3;
        }
        #pragma unroll
        for (int q = 0; q < 5; ++q) {
            int cmask = 32 >> q, tmask = 16 >> q;
            int src = (lane & cmask) ? (lane ^ tmask) : lane;
            a0 = __shfl(a0, src); a1 = __shfl(a1, src);
            a2 = __shfl(a2, src); a3 = __shfl(a3, src);
        }
        {
            bool f = (lane & 1);
            float n0 = f ? a2 : a0, n2 = f ? a0 : a2;
            float n1 = f ? a3 : a1, n3 = f ? a1 : a3;
            a0 = n0; a1 = n1; a2 = n2; a3 = n3;
        }
        { float t = a2; a2 = a3; a3 = t; }
    }

    float part = a0 * a0 + a1 * a1 + a2 * a2 + a3 * a3;
    part = (lane & 32) ? -part : part;
    #pragma unroll
    for (int m = 32; m; m >>= 1) part += __shfl_xor(part, m);
    if (lane == 0) qout[s] = part;
}

// ---------------------------------------------------------------------------
// Tail MLP: 1->64(relu,BN)->32(relu)->16(relu)->1 sigmoid
// ---------------------------------------------------------------------------
__global__ __launch_bounds__(256) void tail_kernel(
    const float* __restrict__ qv,
    const float* __restrict__ w1, const float* __restrict__ b1,
    const float* __restrict__ cg, const float* __restrict__ cb,
    const float* __restrict__ cm, const float* __restrict__ cv,
    const float* __restrict__ w2, const float* __restrict__ b2,
    const float* __restrict__ w3, const float* __restrict__ b3,
    const float* __restrict__ w4, const float* __restrict__ b4,
    float* __restrict__ out)
{
    const int s = blockIdx.x * 256 + threadIdx.x;
    float q = qv[s];

    float acc2[32];
    #pragma unroll
    for (int j = 0; j < 32; ++j) acc2[j] = b2[j];
    for (int i = 0; i < 64; ++i) {
        float z = fmaxf(fmaf(q, w1[i], b1[i]), 0.f);
        z = fmaf(z - cm[i], cg[i] * rsqrtf(cv[i] + 1e-5f), cb[i]);
        #pragma unroll
        for (int j = 0; j < 32; ++j) acc2[j] = fmaf(w2[j * 64 + i], z, acc2[j]);
    }
    float z3[16];
    #pragma unroll
    for (int j = 0; j < 16; ++j) {
        float a = b3[j];
        #pragma unroll
        for (int i = 0; i < 32; ++i) a = fmaf(w3[j * 32 + i], fmaxf(acc2[i], 0.f), a);
        z3[j] = fmaxf(a, 0.f);
    }
    float o = b4[0];
    #pragma unroll
    for (int i = 0; i < 16; ++i) o = fmaf(w4[i], z3[i], o);
    out[s] = 1.f / (1.f + expf(-o));
}

// ---------------------------------------------------------------------------
extern "C" void kernel_launch(void* const* d_in, const int* in_sizes, int n_in,
                              void* d_out, int out_size, void* d_ws, size_t ws_size,
                              hipStream_t stream)
{
    const float* x    = (const float*)d_in[0];
    const float* c1w  = (const float*)d_in[1];
    const float* c1b  = (const float*)d_in[2];
    const float* bn1g = (const float*)d_in[3];
    const float* bn1b = (const float*)d_in[4];
    const float* bn1m = (const float*)d_in[5];
    const float* bn1v = (const float*)d_in[6];
    const float* c2w  = (const float*)d_in[7];
    const float* c2b  = (const float*)d_in[8];
    const float* bn2g = (const float*)d_in[9];
    const float* bn2b = (const float*)d_in[10];
    const float* bn2m = (const float*)d_in[11];
    const float* bn2v = (const float*)d_in[12];
    const float* c3w  = (const float*)d_in[13];
    const float* c3b  = (const float*)d_in[14];
    const float* bn3g = (const float*)d_in[15];
    const float* bn3b = (const float*)d_in[16];
    const float* bn3m = (const float*)d_in[17];
    const float* bn3v = (const float*)d_in[18];
    const float* f1w  = (const float*)d_in[19];
    const float* f1b  = (const float*)d_in[20];
    const float* f2w  = (const float*)d_in[21];
    const float* f2b  = (const float*)d_in[22];
    const float* qw   = (const float*)d_in[23];
    const float* w1   = (const float*)d_in[24];
    const float* b1   = (const float*)d_in[25];
    const float* cg   = (const float*)d_in[26];
    const float* cb   = (const float*)d_in[27];
    const float* cm   = (const float*)d_in[28];
    const float* cv   = (const float*)d_in[29];
    const float* w2   = (const float*)d_in[30];
    const float* b2   = (const float*)d_in[31];
    const float* w3   = (const float*)d_in[32];
    const float* b3   = (const float*)d_in[33];
    const float* w4   = (const float*)d_in[34];
    const float* b4   = (const float*)d_in[35];

    float* ws = (float*)d_ws;
    float* pooled = ws;                                      // 8192*512 f32
    float* a1     = ws + (size_t)BATCH * 512;                // 8192*384
    float* a2     = ws;                                      // reuses pooled
    float* qv     = a1 + (size_t)BATCH * 384;                // 8192
    // wpack overlaps a1's start: consumed by fused_cnn BEFORE fc1 writes a1.
    unsigned short* wpack = (unsigned short*)a1;             // 20480 ush = 40 KB

    prepack_kernel<<<WPACK_TOTAL / 256, 256, 0, stream>>>(c1w, c2w, c3w, wpack);

    fused_cnn_mfma<<<BATCH, 256, 0, stream>>>(
        x, c1b, bn1g, bn1b, bn1m, bn1v,
        c2b, bn2g, bn2b, bn2m, bn2v,
        c3b, bn3g, bn3b, bn3m, bn3v, wpack, pooled);

    dim3 g1(BATCH / 64, 384 / 64);
    fc_kernel<1><<<g1, 256, 0, stream>>>(pooled, f1w, f1b, a1, BATCH, 384, 512);

    dim3 g2(BATCH / 64, 256 / 64);
    fc_kernel<1><<<g2, 256, 0, stream>>>(a1, f2w, f2b, a2, BATCH, 256, 384);

    qsim_kernel<<<BATCH / 4, 256, 0, stream>>>(a2, qw, qv);

    tail_kernel<<<BATCH / 256, 256, 0, stream>>>(
        qv, w1, b1, cg, cb, cm, cv, w2, b2, w3, b3, w4, b4, (float*)d_out);
}

// Round 4
// 166.621 us; speedup vs baseline: 11.2093x; 1.5749x over previous
//
#include <hip/hip_runtime.h>
#include <hip/hip_bf16.h>
#include <math.h>

#define BATCH 8192

typedef __attribute__((ext_vector_type(8))) short bf16x8;
typedef __attribute__((ext_vector_type(4))) float f32x4;
typedef __attribute__((ext_vector_type(16))) float f32x16;

__device__ __forceinline__ unsigned short f2bf(float f) {
    unsigned int u = __builtin_bit_cast(unsigned int, f);
    u = (u + 0x7FFFu + ((u >> 16) & 1u)) >> 16;
    return (unsigned short)u;
}
__device__ __forceinline__ float bf2f(unsigned short h) {
    unsigned int u = ((unsigned int)h) << 16;
    return __builtin_bit_cast(float, u);
}
__device__ __forceinline__ unsigned int pk2bf(float a, float b) {
    return (unsigned int)f2bf(a) | ((unsigned int)f2bf(b) << 16);
}

// ---- conv weight fragment pack (ushorts) ----
// W1: 2 frags. col = 8*hl + oc(0..7). frag0: k=ky*8+kx (ky0..3,kx<5 valid). frag1: k=kx (ky=4).
// W2: 6 frags [ky][hl]. col=oc(16). k=(kx<<3)|ic, kx<3 valid.
// W3: 18 frags [ky][kx][hl], 32x32 layout: col=lane&31=oc, k=8*(lane>>5)+j=ic.
#define W1OFF 0
#define W1FRAGS 2
#define W2OFF (W1OFF + W1FRAGS * 512)
#define W2FRAGS 6
#define W3OFF (W2OFF + W2FRAGS * 512)
#define W3FRAGS 18
#define CPACK_TOTAL (W3OFF + W3FRAGS * 512)          // 13312 ush
#define FC1_FRAGS (24 * 16 * 2)                      // nb=24, ks=16, hl=2
#define FC2_FRAGS (16 * 12 * 2)
#define FC1_TOTAL (FC1_FRAGS * 512)                  // 393216
#define FC2_TOTAL (FC2_FRAGS * 512)                  // 196608
#define ANG_TOTAL 112                                // 56 * (cos,sin)
#define PREP_TOTAL (CPACK_TOTAL + FC1_TOTAL + FC2_TOTAL + ANG_TOTAL)

// ---------------------------------------------------------------------------
__global__ __launch_bounds__(256) void prepack_kernel(
    const float* __restrict__ c1w, const float* __restrict__ c2w,
    const float* __restrict__ c3w, const float* __restrict__ f1w,
    const float* __restrict__ f2w, const float* __restrict__ qw,
    unsigned short* __restrict__ cpack, unsigned short* __restrict__ fpack1,
    unsigned short* __restrict__ fpack2, float* __restrict__ angtab)
{
    int e = blockIdx.x * 256 + threadIdx.x;
    if (e >= PREP_TOTAL) return;

    if (e < CPACK_TOTAL) {
        int f = e >> 9, r = e & 511;
        int l = r >> 3, j = r & 7;
        float w = 0.f; int hl = 0;
        if (f < W1FRAGS) {
            int oc = l & 7; hl = (l >> 3) & 1;
            int k = 8 * (l >> 4) + j;
            int ky, kx;
            if (f == 0) { ky = k >> 3; kx = k & 7; }
            else        { ky = 4;      kx = k; }
            if (kx < 5 && ky < 5) w = c1w[oc * 25 + ky * 5 + kx];
        } else if (f < W1FRAGS + W2FRAGS) {
            int f2 = f - W1FRAGS;
            int ky = f2 >> 1; hl = f2 & 1;
            int k = 8 * (l >> 4) + j;
            int kx = k >> 3, ic = k & 7, oc = l & 15;
            if (kx < 3) w = c2w[((oc * 8 + ic) * 3 + ky) * 3 + kx];
        } else {
            int f3 = f - W1FRAGS - W2FRAGS;      // (ky*3+kx)*2+hl
            int ky = f3 / 6, kx = (f3 / 2) % 3; hl = f3 & 1;
            int oc = l & 31, ic = 8 * (l >> 5) + j;
            w = c3w[((oc * 16 + ic) * 3 + ky) * 3 + kx];
        }
        unsigned short hv = f2bf(w);
        unsigned short lv = f2bf(w - bf2f(hv));
        cpack[e] = hl ? lv : hv;
        return;
    }
    e -= CPACK_TOTAL;
    if (e < FC1_TOTAL) {
        int phi = e >> 9, r = e & 511;
        int l = r >> 3, j = r & 7;
        int hl = phi & 1, ks = (phi >> 1) & 15, nb = phi >> 5;
        int n = nb * 16 + (l & 15);
        int kg = ks * 32 + 8 * (l >> 4) + j;
        float w = f1w[n * 512 + kg];
        unsigned short hv = f2bf(w);
        unsigned short lv = f2bf(w - bf2f(hv));
        fpack1[e] = hl ? lv : hv;
        return;
    }
    e -= FC1_TOTAL;
    if (e < FC2_TOTAL) {
        int phi = e >> 9, r = e & 511;
        int l = r >> 3, j = r & 7;
        int hl = phi & 1, ks = (phi >> 1) % 12, nb = phi / 24;
        int n = nb * 16 + (l & 15);
        int kg = ks * 32 + 8 * (l >> 4) + j;
        float w = f2w[n * 384 + kg];
        unsigned short hv = f2bf(w);
        unsigned short lv = f2bf(w - bf2f(hv));
        fpack2[e] = hl ? lv : hv;
        return;
    }
    e -= FC2_TOTAL;
    {   // angle table: 56 angles -> (cos, sin) of qw/2
        int a = e >> 1;
        float th = 0.5f * qw[a];
        angtab[e] = (e & 1) ? sinf(th) : cosf(th);
    }
}

// ---------------------------------------------------------------------------
// Fused CNN. One block (4 waves) per sample.
// LDS: h1p [34*34][8] bf16; sbuf = xp 68x68 bf16 / h2p [18*18][16] bf16.
// ---------------------------------------------------------------------------
__global__ __launch_bounds__(256) void fused_cnn_mfma(
    const float* __restrict__ x,
    const float* __restrict__ c1b,
    const float* __restrict__ bn1g, const float* __restrict__ bn1b,
    const float* __restrict__ bn1m, const float* __restrict__ bn1v,
    const float* __restrict__ c2b,
    const float* __restrict__ bn2g, const float* __restrict__ bn2b,
    const float* __restrict__ bn2m, const float* __restrict__ bn2v,
    const float* __restrict__ c3b,
    const float* __restrict__ bn3g, const float* __restrict__ bn3b,
    const float* __restrict__ bn3m, const float* __restrict__ bn3v,
    const unsigned short* __restrict__ cpack,
    unsigned short* __restrict__ pooled_bf)
{
    __shared__ unsigned short h1p[9248];   // (34*34)*8
    __shared__ unsigned short sbuf[5200];  // max(68*68, 18*18*16)

    const int tid = threadIdx.x;
    const int lane = tid & 63;
    const int wv = tid >> 6;
    const int n = blockIdx.x;
    const int lrow = lane & 15;
    const int lq = lane >> 4;         // 0..3

    // ---- zero xp + h1p (pads must be 0) ----
    {
        unsigned int* z1 = (unsigned int*)sbuf;
        for (int i = tid; i < 2600; i += 256) z1[i] = 0u;
        unsigned int* z2 = (unsigned int*)h1p;
        for (int i = tid; i < 4624; i += 256) z2[i] = 0u;
    }
    __syncthreads();

    // ---- stage x[n] -> xp bf16 (pad 2) ----
    {
        const float4* xv = (const float4*)(x + (size_t)n * 4096);
        #pragma unroll
        for (int i = 0; i < 4; ++i) {
            int idx = tid + 256 * i;
            float4 v = xv[idx];
            int px = idx * 4;
            int y = px >> 6, xc = px & 63;
            int base = (y + 2) * 68 + xc + 2;  // even
            *(unsigned int*)&sbuf[base]     = pk2bf(v.x, v.y);
            *(unsigned int*)&sbuf[base + 2] = pk2bf(v.z, v.w);
        }
    }
    __syncthreads();

    // ---- conv1: 1->8ch 5x5 s2 p2, out 8x32x32 -> h1p ----
    // MFMA#1: k=ky*8+kx (ky=lq rows), MFMA#2: k=kx (ky=4). col = 8*hl + oc.
    {
        bf16x8 w1f0 = __builtin_bit_cast(bf16x8, *(const uint4*)(cpack + W1OFF + lane * 8));
        bf16x8 w1f1 = __builtin_bit_cast(bf16x8, *(const uint4*)(cpack + W1OFF + 512 + lane * 8));
        int oc = lane & 7;
        float s1 = bn1g[oc] * rsqrtf(bn1v[oc] + 1e-5f);
        float sh1 = (c1b[oc] - bn1m[oc]) * s1 + bn1b[oc];
        #pragma unroll 4
        for (int t = 0; t < 16; ++t) {
            int oy = wv * 8 + (t >> 1), h = t & 1;
            // A1: row (2oy+lq), 8 pixels from col 2*(16h+lrow)
            int u1 = (2 * oy + lq) * 68 + 32 * h + 2 * lrow;
            const unsigned int* p1 = (const unsigned int*)sbuf + (u1 >> 1);
            uint4 d1; d1.x = p1[0]; d1.y = p1[1]; d1.z = p1[2]; d1.w = p1[3];
            // A2: row (2oy+4), 8 pixels from col 2*(16h+lrow)+8*lq
            int u2 = (2 * oy + 4) * 68 + 32 * h + 2 * lrow + 8 * lq;
            const unsigned int* p2 = (const unsigned int*)sbuf + (u2 >> 1);
            uint4 d2; d2.x = p2[0]; d2.y = p2[1]; d2.z = p2[2]; d2.w = p2[3];
            f32x4 acc = {0.f, 0.f, 0.f, 0.f};
            acc = __builtin_amdgcn_mfma_f32_16x16x32_bf16(__builtin_bit_cast(bf16x8, d1), w1f0, acc, 0, 0, 0);
            acc = __builtin_amdgcn_mfma_f32_16x16x32_bf16(__builtin_bit_cast(bf16x8, d2), w1f1, acc, 0, 0, 0);
            #pragma unroll
            for (int r = 0; r < 4; ++r) {
                float v = acc[r] + __shfl_xor(acc[r], 8);
                if ((lane & 8) == 0) {
                    int ox = 16 * h + 4 * lq + r;
                    float yv = fmaxf(fmaf(v, s1, sh1), 0.f);
                    h1p[((oy + 1) * 34 + ox + 1) * 8 + oc] = f2bf(yv);
                }
            }
        }
    }
    __syncthreads();

    // ---- zero h2p region ----
    {
        unsigned int* z = (unsigned int*)sbuf;
        for (int i = tid; i < 2600; i += 256) z[i] = 0u;
    }
    __syncthreads();

    // ---- conv2: 8->16ch 3x3 s2 p1, out 16x16x16 -> h2p ----
    {
        bf16x8 w2f[3][2];
        #pragma unroll
        for (int ky = 0; ky < 3; ++ky)
            #pragma unroll
            for (int hl = 0; hl < 2; ++hl)
                w2f[ky][hl] = __builtin_bit_cast(bf16x8,
                    *(const uint4*)(cpack + W2OFF + (ky * 2 + hl) * 512 + lane * 8));
        int oc = lrow;
        float s2 = bn2g[oc] * rsqrtf(bn2v[oc] + 1e-5f);
        float sh2 = (c2b[oc] - bn2m[oc]) * s2 + bn2b[oc];
        #pragma unroll
        for (int t = 0; t < 4; ++t) {
            int oy = 4 * wv + t;
            f32x4 acc = {0.f, 0.f, 0.f, 0.f};
            #pragma unroll
            for (int ky = 0; ky < 3; ++ky) {
                int iy = 2 * oy + ky;
                int pix = iy * 34 + 2 * lrow + lq;
                bf16x8 a = __builtin_bit_cast(bf16x8, *(const uint4*)(h1p + pix * 8));
                acc = __builtin_amdgcn_mfma_f32_16x16x32_bf16(a, w2f[ky][0], acc, 0, 0, 0);
                acc = __builtin_amdgcn_mfma_f32_16x16x32_bf16(a, w2f[ky][1], acc, 0, 0, 0);
            }
            #pragma unroll
            for (int r = 0; r < 4; ++r) {
                int ox = 4 * lq + r;
                float yv = fmaxf(fmaf(acc[r], s2, sh2), 0.f);
                sbuf[((oy + 1) * 18 + ox + 1) * 16 + oc] = f2bf(yv);
            }
        }
    }
    __syncthreads();

    // ---- conv3: 16->32ch 3x3 s1 p1 (32x32x16 MFMA) + BN/ReLU + 4x4 pool ----
    {
        f32x16 accA = {0.f}, accB = {0.f};
        const int row = lane & 31;           // pixel index within group
        const int khalf = lane >> 5;
        #pragma unroll
        for (int ky = 0; ky < 3; ++ky)
            #pragma unroll
            for (int kx = 0; kx < 3; ++kx) {
                int fb = (ky * 3 + kx) * 2;
                bf16x8 bh = __builtin_bit_cast(bf16x8, *(const uint4*)(cpack + W3OFF + fb * 512 + lane * 8));
                bf16x8 bl = __builtin_bit_cast(bf16x8, *(const uint4*)(cpack + W3OFF + (fb + 1) * 512 + lane * 8));
                // g = 0: rows 4wv + {0,1}
                {
                    int pix = (4 * wv + 0 + (row >> 4) + ky) * 18 + (row & 15) + kx;
                    bf16x8 a = __builtin_bit_cast(bf16x8, *(const uint4*)(sbuf + pix * 16 + khalf * 8));
                    accA = __builtin_amdgcn_mfma_f32_32x32x16_bf16(a, bh, accA, 0, 0, 0);
                    accA = __builtin_amdgcn_mfma_f32_32x32x16_bf16(a, bl, accA, 0, 0, 0);
                }
                // g = 1: rows 4wv + {2,3}
                {
                    int pix = (4 * wv + 2 + (row >> 4) + ky) * 18 + (row & 15) + kx;
                    bf16x8 a = __builtin_bit_cast(bf16x8, *(const uint4*)(sbuf + pix * 16 + khalf * 8));
                    accB = __builtin_amdgcn_mfma_f32_32x32x16_bf16(a, bh, accB, 0, 0, 0);
                    accB = __builtin_amdgcn_mfma_f32_32x32x16_bf16(a, bl, accB, 0, 0, 0);
                }
            }
        int oc = lane & 31;
        float s3 = bn3g[oc] * rsqrtf(bn3v[oc] + 1e-5f);
        float sh3 = (c3b[oc] - bn3m[oc]) * s3 + bn3b[oc];
        float pool0 = 0.f, pool1 = 0.f;
        #pragma unroll
        for (int r = 0; r < 16; ++r) {
            float va = fmaxf(fmaf(accA[r], s3, sh3), 0.f);
            float vb = fmaxf(fmaf(accB[r], s3, sh3), 0.f);
            if (((r >> 2) & 1) == 0) { pool0 += va + vb; } else { pool1 += va + vb; }
        }
        int base = n * 512 + oc * 16 + wv * 4 + khalf;
        pooled_bf[base]     = f2bf(pool0 * (1.f / 16.f));
        pooled_bf[base + 2] = f2bf(pool1 * (1.f / 16.f));
    }
}

// ---------------------------------------------------------------------------
// FC GEMM (bf16 MFMA, hi/lo packed weights from global):
// out[M,N] = relu(A[M,K] @ W[N,K]^T + bias). Tile 128x64, BK=64, 4 waves (2x2).
// ---------------------------------------------------------------------------
template <int OUT_BF16>
__global__ __launch_bounds__(256) void fc_mfma(
    const unsigned short* __restrict__ Abf,
    const unsigned short* __restrict__ wfrag,
    const float* __restrict__ bias, void* __restrict__ out,
    int N, int K)
{
    __shared__ unsigned short As[8192];   // [128][64] ush, XOR-swizzled
    const int tid = threadIdx.x;
    const int lane = tid & 63;
    const int wv = tid >> 6;
    const int wm = wv >> 1, wn = wv & 1;
    const int bm = blockIdx.x * 128;
    const int bn = blockIdx.y * 64;
    const int lq = lane >> 4;
    const int lr = lane & 15;
    const int KS = K >> 5;                // k-steps of 32

    f32x4 acc[4][2];
    #pragma unroll
    for (int i = 0; i < 4; ++i) { acc[i][0] = (f32x4){0,0,0,0}; acc[i][1] = (f32x4){0,0,0,0}; }

    for (int k0 = 0; k0 < K; k0 += 64) {
        // stage A[128][64]: thread t -> 4 chunks of 16B
        #pragma unroll
        for (int i = 0; i < 4; ++i) {
            int q = tid * 4 + i;              // 0..1023
            int row = q >> 3, kc = q & 7;
            uint4 v = *(const uint4*)(Abf + (size_t)(bm + row) * K + k0 + 8 * kc);
            int byte = (row * 128 + 16 * kc) ^ ((row & 7) << 4);
            *(uint4*)((char*)As + byte) = v;
        }
        __syncthreads();
        #pragma unroll
        for (int kk = 0; kk < 2; ++kk) {
            bf16x8 af[4];
            #pragma unroll
            for (int mf = 0; mf < 4; ++mf) {
                int ml = wm * 64 + mf * 16 + lr;
                int byte = (ml * 128 + 64 * kk + 16 * lq) ^ ((ml & 7) << 4);
                af[mf] = __builtin_bit_cast(bf16x8, *(const uint4*)((char*)As + byte));
            }
            int ks = (k0 >> 5) + kk;
            #pragma unroll
            for (int nf = 0; nf < 2; ++nf) {
                int nb = (bn >> 4) + wn * 2 + nf;
                const unsigned short* fb = wfrag + ((size_t)(nb * KS + ks) * 2) * 512 + lane * 8;
                bf16x8 bh = __builtin_bit_cast(bf16x8, *(const uint4*)fb);
                bf16x8 bl = __builtin_bit_cast(bf16x8, *(const uint4*)(fb + 512));
                #pragma unroll
                for (int mf = 0; mf < 4; ++mf) {
                    acc[mf][nf] = __builtin_amdgcn_mfma_f32_16x16x32_bf16(af[mf], bh, acc[mf][nf], 0, 0, 0);
                    acc[mf][nf] = __builtin_amdgcn_mfma_f32_16x16x32_bf16(af[mf], bl, acc[mf][nf], 0, 0, 0);
                }
            }
        }
        __syncthreads();
    }

    #pragma unroll
    for (int nf = 0; nf < 2; ++nf) {
        int nn = bn + wn * 32 + nf * 16 + lr;
        float bv = bias[nn];
        #pragma unroll
        for (int mf = 0; mf < 4; ++mf)
            #pragma unroll
            for (int r = 0; r < 4; ++r) {
                int m = bm + wm * 64 + mf * 16 + 4 * lq + r;
                float v = fmaxf(acc[mf][nf][r] + bv, 0.f);
                if (OUT_BF16) ((unsigned short*)out)[(size_t)m * N + nn] = f2bf(v);
                else          ((float*)out)[(size_t)m * N + nn] = v;
            }
    }
}

// ---------------------------------------------------------------------------
// L2-norm + 8-qubit/7-layer qsim + fused tail MLP. One wave per sample.
// ---------------------------------------------------------------------------
__global__ __launch_bounds__(256) void qsim_tail_kernel(
    const float* __restrict__ feats, const float* __restrict__ angtab,
    const float* __restrict__ w1, const float* __restrict__ b1,
    const float* __restrict__ cg, const float* __restrict__ cb,
    const float* __restrict__ cm, const float* __restrict__ cv,
    const float* __restrict__ w2, const float* __restrict__ b2,
    const float* __restrict__ w3, const float* __restrict__ b3,
    const float* __restrict__ w4, const float* __restrict__ b4,
    float* __restrict__ out)
{
    const int lane = threadIdx.x & 63;
    const int wid = threadIdx.x >> 6;
    const int s = blockIdx.x * 4 + wid;

    float4 v = *(const float4*)(feats + (size_t)s * 256 + lane * 4);
    float a0 = v.x, a1 = v.y, a2 = v.z, a3 = v.w;

    float ss = a0 * a0 + a1 * a1 + a2 * a2 + a3 * a3;
    #pragma unroll
    for (int m = 32; m; m >>= 1) ss += __shfl_xor(ss, m);
    float inv = 1.f / fmaxf(sqrtf(ss), 1e-12f);
    a0 *= inv; a1 *= inv; a2 *= inv; a3 *= inv;

    for (int l = 0; l < 7; ++l) {
        #pragma unroll
        for (int q = 0; q < 6; ++q) {
            float cs = angtab[(l * 8 + q) * 2], sn = angtab[(l * 8 + q) * 2 + 1];
            int mask = 32 >> q;
            float sg = (lane & mask) ? sn : -sn;
            float b0 = __shfl_xor(a0, mask), b1v = __shfl_xor(a1, mask);
            float b2v = __shfl_xor(a2, mask), b3v = __shfl_xor(a3, mask);
            a0 = fmaf(sg, b0, cs * a0); a1 = fmaf(sg, b1v, cs * a1);
            a2 = fmaf(sg, b2v, cs * a2); a3 = fmaf(sg, b3v, cs * a3);
        }
        {
            float cs = angtab[(l * 8 + 6) * 2], sn = angtab[(l * 8 + 6) * 2 + 1];
            float n0 = cs * a0 - sn * a2, n2 = fmaf(sn, a0, cs * a2);
            float n1 = cs * a1 - sn * a3, n3 = fmaf(sn, a1, cs * a3);
            a0 = n0; a1 = n1; a2 = n2; a3 = n3;
        }
        {
            float cs = angtab[(l * 8 + 7) * 2], sn = angtab[(l * 8 + 7) * 2 + 1];
            float n0 = cs * a0 - sn * a1, n1 = fmaf(sn, a0, cs * a1);
            float n2 = cs * a2 - sn * a3, n3 = fmaf(sn, a2, cs * a3);
            a0 = n0; a1 = n1; a2 = n2; a3 = n3;
        }
        #pragma unroll
        for (int q = 0; q < 5; ++q) {
            int cmask = 32 >> q, tmask = 16 >> q;
            int src = (lane & cmask) ? (lane ^ tmask) : lane;
            a0 = __shfl(a0, src); a1 = __shfl(a1, src);
            a2 = __shfl(a2, src); a3 = __shfl(a3, src);
        }
        {
            bool f = (lane & 1);
            float n0 = f ? a2 : a0, n2 = f ? a0 : a2;
            float n1 = f ? a3 : a1, n3 = f ? a1 : a3;
            a0 = n0; a1 = n1; a2 = n2; a3 = n3;
        }
        { float t = a2; a2 = a3; a3 = t; }
    }

    float part = a0 * a0 + a1 * a1 + a2 * a2 + a3 * a3;
    part = (lane & 32) ? -part : part;
    #pragma unroll
    for (int m = 32; m; m >>= 1) part += __shfl_xor(part, m);
    float q = part;   // all lanes hold <Z_0>

    // ---- fused tail MLP, wave-parallel ----
    // L1 (64): unit i = lane
    float z = fmaxf(fmaf(q, w1[lane], b1[lane]), 0.f);
    z = fmaf(z - cm[lane], cg[lane] * rsqrtf(cv[lane] + 1e-5f), cb[lane]);
    // L2 (32): j = lane&31, half h = lane>>5
    {
        int j = lane & 31, hb = lane & 32;
        float acc = 0.f;
        #pragma unroll
        for (int t = 0; t < 32; ++t)
            acc = fmaf(w2[j * 64 + hb + t], __shfl(z, hb + t), acc);
        acc += __shfl_xor(acc, 32);
        z = fmaxf(acc + b2[j], 0.f);          // a2_j, duplicated in halves
    }
    // L3 (16): j3 = lane&15, quarter qh = (lane>>4)&3
    {
        int j3 = lane & 15, qh = (lane >> 4) & 3;
        float p = 0.f;
        #pragma unroll
        for (int t = 0; t < 8; ++t)
            p = fmaf(w3[j3 * 32 + 8 * qh + t], __shfl(z, 8 * qh + t), p);
        p += __shfl_xor(p, 16);
        p += __shfl_xor(p, 32);
        z = fmaxf(p + b3[j3], 0.f);           // z3_j3, duplicated x4
    }
    // L4: dot over j3 within each 16-lane group
    {
        float t4 = w4[lane & 15] * z;
        t4 += __shfl_xor(t4, 1); t4 += __shfl_xor(t4, 2);
        t4 += __shfl_xor(t4, 4); t4 += __shfl_xor(t4, 8);
        float o = t4 + b4[0];
        if (lane == 0) out[s] = 1.f / (1.f + expf(-o));
    }
}

// ---------------------------------------------------------------------------
extern "C" void kernel_launch(void* const* d_in, const int* in_sizes, int n_in,
                              void* d_out, int out_size, void* d_ws, size_t ws_size,
                              hipStream_t stream)
{
    const float* x    = (const float*)d_in[0];
    const float* c1w  = (const float*)d_in[1];
    const float* c1b  = (const float*)d_in[2];
    const float* bn1g = (const float*)d_in[3];
    const float* bn1b = (const float*)d_in[4];
    const float* bn1m = (const float*)d_in[5];
    const float* bn1v = (const float*)d_in[6];
    const float* c2w  = (const float*)d_in[7];
    const float* c2b  = (const float*)d_in[8];
    const float* bn2g = (const float*)d_in[9];
    const float* bn2b = (const float*)d_in[10];
    const float* bn2m = (const float*)d_in[11];
    const float* bn2v = (const float*)d_in[12];
    const float* c3w  = (const float*)d_in[13];
    const float* c3b  = (const float*)d_in[14];
    const float* bn3g = (const float*)d_in[15];
    const float* bn3b = (const float*)d_in[16];
    const float* bn3m = (const float*)d_in[17];
    const float* bn3v = (const float*)d_in[18];
    const float* f1w  = (const float*)d_in[19];
    const float* f1b  = (const float*)d_in[20];
    const float* f2w  = (const float*)d_in[21];
    const float* f2b  = (const float*)d_in[22];
    const float* qw   = (const float*)d_in[23];
    const float* w1   = (const float*)d_in[24];
    const float* b1   = (const float*)d_in[25];
    const float* cg   = (const float*)d_in[26];
    const float* cb   = (const float*)d_in[27];
    const float* cm   = (const float*)d_in[28];
    const float* cv   = (const float*)d_in[29];
    const float* w2   = (const float*)d_in[30];
    const float* b2   = (const float*)d_in[31];
    const float* w3   = (const float*)d_in[32];
    const float* b3   = (const float*)d_in[33];
    const float* w4   = (const float*)d_in[34];
    const float* b4   = (const float*)d_in[35];

    unsigned short* ws = (unsigned short*)d_ws;
    unsigned short* pooled_bf = ws;                              // 8192*512 ush
    unsigned short* a1_bf     = pooled_bf + (size_t)BATCH * 512; // 8192*384 ush
    float*          a2        = (float*)(a1_bf + (size_t)BATCH * 384); // 8192*256 f32
    unsigned short* cpack     = (unsigned short*)(a2 + (size_t)BATCH * 256);
    unsigned short* fpack1    = cpack + CPACK_TOTAL;
    unsigned short* fpack2    = fpack1 + FC1_TOTAL;
    float*          angtab    = (float*)(fpack2 + FC2_TOTAL);

    prepack_kernel<<<(PREP_TOTAL + 255) / 256, 256, 0, stream>>>(
        c1w, c2w, c3w, f1w, f2w, qw, cpack, fpack1, fpack2, angtab);

    fused_cnn_mfma<<<BATCH, 256, 0, stream>>>(
        x, c1b, bn1g, bn1b, bn1m, bn1v,
        c2b, bn2g, bn2b, bn2m, bn2v,
        c3b, bn3g, bn3b, bn3m, bn3v, cpack, pooled_bf);

    dim3 g1(BATCH / 128, 384 / 64);
    fc_mfma<1><<<g1, 256, 0, stream>>>(pooled_bf, fpack1, f1b, a1_bf, 384, 512);

    dim3 g2(BATCH / 128, 256 / 64);
    fc_mfma<0><<<g2, 256, 0, stream>>>(a1_bf, fpack2, f2b, a2, 256, 384);

    qsim_tail_kernel<<<BATCH / 4, 256, 0, stream>>>(
        a2, angtab, w1, b1, cg, cb, cm, cv, w2, b2, w3, b3, w4, b4, (float*)d_out);
}

// Round 5
// 151.553 us; speedup vs baseline: 12.3238x; 1.0994x over previous
//
#include <hip/hip_runtime.h>
#include <hip/hip_bf16.h>
#include <math.h>

#define BATCH 8192

typedef __attribute__((ext_vector_type(8))) short bf16x8;
typedef __attribute__((ext_vector_type(4))) float f32x4;
typedef __attribute__((ext_vector_type(16))) float f32x16;

__device__ __forceinline__ unsigned short f2bf(float f) {
    unsigned int u = __builtin_bit_cast(unsigned int, f);
    u = (u + 0x7FFFu + ((u >> 16) & 1u)) >> 16;
    return (unsigned short)u;
}
__device__ __forceinline__ float bf2f(unsigned short h) {
    unsigned int u = ((unsigned int)h) << 16;
    return __builtin_bit_cast(float, u);
}
__device__ __forceinline__ unsigned int pk2bf(float a, float b) {
    return (unsigned int)f2bf(a) | ((unsigned int)f2bf(b) << 16);
}

// ---- conv weight fragment pack (ushorts) ----
// W1: 4 frags [sel][hl]: col=oc(0..7, 8-15 zero). sel0: k=ky*8+kx (ky<4,kx<5). sel1: k=kx (ky=4).
// W2: 6 frags [ky][hl]. col=oc(16). k=(kx<<3)|ic, kx<3 valid.
// W3: 18 frags [ky][kx][hl], 32x32: col=lane&31=oc, k=8*(lane>>5)+j=ic.
#define W1OFF 0
#define W1FRAGS 4
#define W2OFF (W1OFF + W1FRAGS * 512)
#define W2FRAGS 6
#define W3OFF (W2OFF + W2FRAGS * 512)
#define W3FRAGS 18
#define CPACK_TOTAL (W3OFF + W3FRAGS * 512)          // 14336 ush
#define FC1_FRAGS (24 * 16 * 2)
#define FC2_FRAGS (16 * 12 * 2)
#define FC1_TOTAL (FC1_FRAGS * 512)
#define FC2_TOTAL (FC2_FRAGS * 512)
#define ANG_TOTAL 112
#define PREP_TOTAL (CPACK_TOTAL + FC1_TOTAL + FC2_TOTAL + ANG_TOTAL)

// ---------------------------------------------------------------------------
__global__ __launch_bounds__(256) void prepack_kernel(
    const float* __restrict__ c1w, const float* __restrict__ c2w,
    const float* __restrict__ c3w, const float* __restrict__ f1w,
    const float* __restrict__ f2w, const float* __restrict__ qw,
    unsigned short* __restrict__ cpack, unsigned short* __restrict__ fpack1,
    unsigned short* __restrict__ fpack2, float* __restrict__ angtab)
{
    int e = blockIdx.x * 256 + threadIdx.x;
    if (e >= PREP_TOTAL) return;

    if (e < CPACK_TOTAL) {
        int f = e >> 9, r = e & 511;
        int l = r >> 3, j = r & 7;
        float w = 0.f; int hl = 0;
        if (f < W1FRAGS) {
            int sel = f >> 1; hl = f & 1;
            int oc = l & 15;
            int k = 8 * (l >> 4) + j;
            int ky, kx;
            if (sel == 0) { ky = k >> 3; kx = k & 7; }
            else          { ky = 4;      kx = k; }
            if (kx < 5 && ky < 5 && oc < 8) w = c1w[oc * 25 + ky * 5 + kx];
        } else if (f < W1FRAGS + W2FRAGS) {
            int f2 = f - W1FRAGS;
            int ky = f2 >> 1; hl = f2 & 1;
            int k = 8 * (l >> 4) + j;
            int kx = k >> 3, ic = k & 7, oc = l & 15;
            if (kx < 3) w = c2w[((oc * 8 + ic) * 3 + ky) * 3 + kx];
        } else {
            int f3 = f - W1FRAGS - W2FRAGS;      // (ky*3+kx)*2+hl
            int ky = f3 / 6, kx = (f3 / 2) % 3; hl = f3 & 1;
            int oc = l & 31, ic = 8 * (l >> 5) + j;
            w = c3w[((oc * 16 + ic) * 3 + ky) * 3 + kx];
        }
        unsigned short hv = f2bf(w);
        unsigned short lv = f2bf(w - bf2f(hv));
        cpack[e] = hl ? lv : hv;
        return;
    }
    e -= CPACK_TOTAL;
    if (e < FC1_TOTAL) {
        int phi = e >> 9, r = e & 511;
        int l = r >> 3, j = r & 7;
        int hl = phi & 1, ks = (phi >> 1) & 15, nb = phi >> 5;
        int n = nb * 16 + (l & 15);
        int kg = ks * 32 + 8 * (l >> 4) + j;
        float w = f1w[n * 512 + kg];
        unsigned short hv = f2bf(w);
        unsigned short lv = f2bf(w - bf2f(hv));
        fpack1[e] = hl ? lv : hv;
        return;
    }
    e -= FC1_TOTAL;
    if (e < FC2_TOTAL) {
        int phi = e >> 9, r = e & 511;
        int l = r >> 3, j = r & 7;
        int hl = phi & 1, ks = (phi >> 1) % 12, nb = phi / 24;
        int n = nb * 16 + (l & 15);
        int kg = ks * 32 + 8 * (l >> 4) + j;
        float w = f2w[n * 384 + kg];
        unsigned short hv = f2bf(w);
        unsigned short lv = f2bf(w - bf2f(hv));
        fpack2[e] = hl ? lv : hv;
        return;
    }
    e -= FC2_TOTAL;
    {
        int a = e >> 1;
        float th = 0.5f * qw[a];
        angtab[e] = (e & 1) ? sinf(th) : cosf(th);
    }
}

// ---------------------------------------------------------------------------
// Fused CNN. One block (4 waves) per sample. 3 barriers.
// LDS: h1p [34*34+pad][8] bf16, XOR-swizzled at uint4 granularity;
//      sbuf = xp 68x68 bf16 / h2p [18*18][16] bf16.
// ---------------------------------------------------------------------------
__global__ __launch_bounds__(256) void fused_cnn_mfma(
    const float* __restrict__ x,
    const float* __restrict__ c1b,
    const float* __restrict__ bn1g, const float* __restrict__ bn1b,
    const float* __restrict__ bn1m, const float* __restrict__ bn1v,
    const float* __restrict__ c2b,
    const float* __restrict__ bn2g, const float* __restrict__ bn2b,
    const float* __restrict__ bn2m, const float* __restrict__ bn2v,
    const float* __restrict__ c3b,
    const float* __restrict__ bn3g, const float* __restrict__ bn3b,
    const float* __restrict__ bn3m, const float* __restrict__ bn3v,
    const unsigned short* __restrict__ cpack,
    unsigned short* __restrict__ pooled_bf)
{
    __shared__ __align__(16) unsigned short h1p[9280];   // 1160 uint4 (34*34=1156 + swz pad)
    __shared__ __align__(16) unsigned short sbuf[5200];  // xp 68*68=4624 / h2p 18*18*16=5184

    uint4* h1p4 = (uint4*)h1p;
    uint4* sbuf4 = (uint4*)sbuf;
    unsigned int* sd = (unsigned int*)sbuf;

    const int tid = threadIdx.x;
    const int lane = tid & 63;
    const int wv = tid >> 6;
    const int n = blockIdx.x;
    const int lrow = lane & 15;
    const int lq = lane >> 4;         // 0..3

    // ---- P0: stage x interior + zero xp pads + zero h1p pads ----
    {
        const float4* xv = (const float4*)(x + (size_t)n * 4096);
        #pragma unroll
        for (int i = 0; i < 4; ++i) {
            int idx = tid + 256 * i;
            float4 v = xv[idx];
            int px = idx * 4;
            int y = px >> 6, xc = px & 63;
            int d = (y + 2) * 34 + (xc >> 1) + 1;
            sd[d]     = pk2bf(v.x, v.y);
            sd[d + 1] = pk2bf(v.z, v.w);
        }
        // xp pads (dwords): rows 0-1, rows 66-67, side cols
        if (tid < 68) sd[tid] = 0u;
        if (tid < 68) sd[2244 + tid] = 0u;
        if (tid < 128) { int r = 2 + (tid & 63); sd[r * 34 + ((tid >> 6) ? 33 : 0)] = 0u; }
        // h1p pads: 132 ring pixels, swizzled uint4 stores
        if (tid < 132) {
            int p;
            if (tid < 34) p = tid;
            else if (tid < 68) p = 33 * 34 + (tid - 34);
            else { int r = 1 + ((tid - 68) & 31); int side = (tid - 68) >> 5; p = r * 34 + side * 33; }
            h1p4[p ^ ((p >> 1) & 7)] = (uint4){0u, 0u, 0u, 0u};
        }
    }
    __syncthreads();   // B1

    // ---- conv1: 1->8ch 5x5 s2 p2, out 8x32x32 -> h1p (swizzled) ----
    // 4 MFMAs/t: (f0h,f0l) on A1 [k=8*ky+kx rows 2oy+lq], (f1h,f1l) on A2 [k=kx row 2oy+4].
    // Only k-slots j<5 carry weight -> 3 dword reads per fragment, reg3=0.
    {
        bf16x8 wf[4];
        #pragma unroll
        for (int fi = 0; fi < 4; ++fi)
            wf[fi] = __builtin_bit_cast(bf16x8, *(const uint4*)(cpack + W1OFF + fi * 512 + lane * 8));
        int oce = lrow & 7;
        float s1 = bn1g[oce] * rsqrtf(bn1v[oce] + 1e-5f);
        float sh1 = (c1b[oce] - bn1m[oce]) * s1 + bn1b[oce];
        #pragma unroll 4
        for (int t = 0; t < 16; ++t) {
            int oy = wv * 8 + (t >> 1), h = t & 1;
            int a1 = (2 * oy + lq) * 34 + 16 * h + lrow;
            uint4 d1; d1.x = sd[a1]; d1.y = sd[a1 + 1]; d1.z = sd[a1 + 2]; d1.w = 0u;
            int a2 = (2 * oy + 4) * 34 + 16 * h + lrow;   // lq-invariant -> broadcast
            uint4 d2; d2.x = sd[a2]; d2.y = sd[a2 + 1]; d2.z = sd[a2 + 2]; d2.w = 0u;
            f32x4 acc = {0.f, 0.f, 0.f, 0.f};
            acc = __builtin_amdgcn_mfma_f32_16x16x32_bf16(__builtin_bit_cast(bf16x8, d1), wf[0], acc, 0, 0, 0);
            acc = __builtin_amdgcn_mfma_f32_16x16x32_bf16(__builtin_bit_cast(bf16x8, d1), wf[1], acc, 0, 0, 0);
            acc = __builtin_amdgcn_mfma_f32_16x16x32_bf16(__builtin_bit_cast(bf16x8, d2), wf[2], acc, 0, 0, 0);
            acc = __builtin_amdgcn_mfma_f32_16x16x32_bf16(__builtin_bit_cast(bf16x8, d2), wf[3], acc, 0, 0, 0);
            if (lrow < 8) {
                #pragma unroll
                for (int r = 0; r < 4; ++r) {
                    int ox = 16 * h + 4 * lq + r;
                    int p = (oy + 1) * 34 + ox + 1;
                    float yv = fmaxf(fmaf(acc[r], s1, sh1), 0.f);
                    h1p[(p ^ ((p >> 1) & 7)) * 8 + lrow] = f2bf(yv);
                }
            }
        }
    }
    __syncthreads();   // B2

    // ---- P2: zero h2p pads + conv2 ----
    {
        if (tid < 136) {
            int pp = tid >> 1, half = tid & 1;
            int p;
            if (pp < 18) p = pp;
            else if (pp < 36) p = 17 * 18 + (pp - 18);
            else { int r = 1 + ((pp - 36) & 15); int side = (pp - 36) >> 4; p = r * 18 + side * 17; }
            sbuf4[2 * p + half] = (uint4){0u, 0u, 0u, 0u};
        }
        bf16x8 w2f[3][2];
        #pragma unroll
        for (int ky = 0; ky < 3; ++ky)
            #pragma unroll
            for (int hl = 0; hl < 2; ++hl)
                w2f[ky][hl] = __builtin_bit_cast(bf16x8,
                    *(const uint4*)(cpack + W2OFF + (ky * 2 + hl) * 512 + lane * 8));
        int oc = lrow;
        float s2 = bn2g[oc] * rsqrtf(bn2v[oc] + 1e-5f);
        float sh2 = (c2b[oc] - bn2m[oc]) * s2 + bn2b[oc];
        int lqe = (lq == 3) ? 0 : lq;      // kx=3 group is zero-weight -> broadcast
        #pragma unroll
        for (int t = 0; t < 4; ++t) {
            int oy = 4 * wv + t;
            f32x4 acc = {0.f, 0.f, 0.f, 0.f};
            #pragma unroll
            for (int ky = 0; ky < 3; ++ky) {
                int iy = 2 * oy + ky;
                int p = iy * 34 + 2 * lrow + lqe;
                bf16x8 a = __builtin_bit_cast(bf16x8, h1p4[p ^ ((p >> 1) & 7)]);
                acc = __builtin_amdgcn_mfma_f32_16x16x32_bf16(a, w2f[ky][0], acc, 0, 0, 0);
                acc = __builtin_amdgcn_mfma_f32_16x16x32_bf16(a, w2f[ky][1], acc, 0, 0, 0);
            }
            #pragma unroll
            for (int r = 0; r < 4; ++r) {
                int ox = 4 * lq + r;
                float yv = fmaxf(fmaf(acc[r], s2, sh2), 0.f);
                sbuf[((oy + 1) * 18 + ox + 1) * 16 + oc] = f2bf(yv);
            }
        }
    }
    __syncthreads();   // B3

    // ---- conv3: 16->32ch 3x3 s1 p1 (32x32x16 MFMA) + BN/ReLU + 4x4 pool ----
    {
        f32x16 accA = {0.f}, accB = {0.f};
        const int row = lane & 31;
        const int khalf = lane >> 5;
        #pragma unroll
        for (int ky = 0; ky < 3; ++ky)
            #pragma unroll
            for (int kx = 0; kx < 3; ++kx) {
                int fb = (ky * 3 + kx) * 2;
                bf16x8 bh = __builtin_bit_cast(bf16x8, *(const uint4*)(cpack + W3OFF + fb * 512 + lane * 8));
                bf16x8 bl = __builtin_bit_cast(bf16x8, *(const uint4*)(cpack + W3OFF + (fb + 1) * 512 + lane * 8));
                {
                    int pix = (4 * wv + 0 + (row >> 4) + ky) * 18 + (row & 15) + kx;
                    bf16x8 a = __builtin_bit_cast(bf16x8, *(const uint4*)(sbuf + pix * 16 + khalf * 8));
                    accA = __builtin_amdgcn_mfma_f32_32x32x16_bf16(a, bh, accA, 0, 0, 0);
                    accA = __builtin_amdgcn_mfma_f32_32x32x16_bf16(a, bl, accA, 0, 0, 0);
                }
                {
                    int pix = (4 * wv + 2 + (row >> 4) + ky) * 18 + (row & 15) + kx;
                    bf16x8 a = __builtin_bit_cast(bf16x8, *(const uint4*)(sbuf + pix * 16 + khalf * 8));
                    accB = __builtin_amdgcn_mfma_f32_32x32x16_bf16(a, bh, accB, 0, 0, 0);
                    accB = __builtin_amdgcn_mfma_f32_32x32x16_bf16(a, bl, accB, 0, 0, 0);
                }
            }
        int oc = lane & 31;
        float s3 = bn3g[oc] * rsqrtf(bn3v[oc] + 1e-5f);
        float sh3 = (c3b[oc] - bn3m[oc]) * s3 + bn3b[oc];
        float pool0 = 0.f, pool1 = 0.f;
        #pragma unroll
        for (int r = 0; r < 16; ++r) {
            float va = fmaxf(fmaf(accA[r], s3, sh3), 0.f);
            float vb = fmaxf(fmaf(accB[r], s3, sh3), 0.f);
            if (((r >> 2) & 1) == 0) { pool0 += va + vb; } else { pool1 += va + vb; }
        }
        int base = n * 512 + oc * 16 + wv * 4 + khalf;
        pooled_bf[base]     = f2bf(pool0 * (1.f / 16.f));
        pooled_bf[base + 2] = f2bf(pool1 * (1.f / 16.f));
    }
}

// ---------------------------------------------------------------------------
// FC GEMM (bf16 MFMA, hi/lo packed weights from global):
// out[M,N] = relu(A[M,K] @ W[N,K]^T + bias). Tile 128x64, BK=64, 4 waves (2x2).
// ---------------------------------------------------------------------------
template <int OUT_BF16>
__global__ __launch_bounds__(256) void fc_mfma(
    const unsigned short* __restrict__ Abf,
    const unsigned short* __restrict__ wfrag,
    const float* __restrict__ bias, void* __restrict__ out,
    int N, int K)
{
    __shared__ __align__(16) unsigned short As[8192];   // [128][64], XOR-swizzled
    const int tid = threadIdx.x;
    const int lane = tid & 63;
    const int wv = tid >> 6;
    const int wm = wv >> 1, wn = wv & 1;
    const int bm = blockIdx.x * 128;
    const int bn = blockIdx.y * 64;
    const int lq = lane >> 4;
    const int lr = lane & 15;
    const int KS = K >> 5;

    f32x4 acc[4][2];
    #pragma unroll
    for (int i = 0; i < 4; ++i) { acc[i][0] = (f32x4){0,0,0,0}; acc[i][1] = (f32x4){0,0,0,0}; }

    for (int k0 = 0; k0 < K; k0 += 64) {
        #pragma unroll
        for (int i = 0; i < 4; ++i) {
            int q = tid * 4 + i;
            int row = q >> 3, kc = q & 7;
            uint4 v = *(const uint4*)(Abf + (size_t)(bm + row) * K + k0 + 8 * kc);
            int byte = (row * 128 + 16 * kc) ^ ((row & 7) << 4);
            *(uint4*)((char*)As + byte) = v;
        }
        __syncthreads();
        #pragma unroll
        for (int kk = 0; kk < 2; ++kk) {
            bf16x8 af[4];
            #pragma unroll
            for (int mf = 0; mf < 4; ++mf) {
                int ml = wm * 64 + mf * 16 + lr;
                int byte = (ml * 128 + 64 * kk + 16 * lq) ^ ((ml & 7) << 4);
                af[mf] = __builtin_bit_cast(bf16x8, *(const uint4*)((char*)As + byte));
            }
            int ks = (k0 >> 5) + kk;
            #pragma unroll
            for (int nf = 0; nf < 2; ++nf) {
                int nb = (bn >> 4) + wn * 2 + nf;
                const unsigned short* fb = wfrag + ((size_t)(nb * KS + ks) * 2) * 512 + lane * 8;
                bf16x8 bh = __builtin_bit_cast(bf16x8, *(const uint4*)fb);
                bf16x8 bl = __builtin_bit_cast(bf16x8, *(const uint4*)(fb + 512));
                #pragma unroll
                for (int mf = 0; mf < 4; ++mf) {
                    acc[mf][nf] = __builtin_amdgcn_mfma_f32_16x16x32_bf16(af[mf], bh, acc[mf][nf], 0, 0, 0);
                    acc[mf][nf] = __builtin_amdgcn_mfma_f32_16x16x32_bf16(af[mf], bl, acc[mf][nf], 0, 0, 0);
                }
            }
        }
        __syncthreads();
    }

    #pragma unroll
    for (int nf = 0; nf < 2; ++nf) {
        int nn = bn + wn * 32 + nf * 16 + lr;
        float bv = bias[nn];
        #pragma unroll
        for (int mf = 0; mf < 4; ++mf)
            #pragma unroll
            for (int r = 0; r < 4; ++r) {
                int m = bm + wm * 64 + mf * 16 + 4 * lq + r;
                float v = fmaxf(acc[mf][nf][r] + bv, 0.f);
                if (OUT_BF16) ((unsigned short*)out)[(size_t)m * N + nn] = f2bf(v);
                else          ((float*)out)[(size_t)m * N + nn] = v;
            }
    }
}

// ---------------------------------------------------------------------------
// L2-norm + 8-qubit/7-layer qsim + fused tail MLP. One wave per sample.
// ---------------------------------------------------------------------------
__global__ __launch_bounds__(256) void qsim_tail_kernel(
    const float* __restrict__ feats, const float* __restrict__ angtab,
    const float* __restrict__ w1, const float* __restrict__ b1,
    const float* __restrict__ cg, const float* __restrict__ cb,
    const float* __restrict__ cm, const float* __restrict__ cv,
    const float* __restrict__ w2, const float* __restrict__ b2,
    const float* __restrict__ w3, const float* __restrict__ b3,
    const float* __restrict__ w4, const float* __restrict__ b4,
    float* __restrict__ out)
{
    const int lane = threadIdx.x & 63;
    const int wid = threadIdx.x >> 6;
    const int s = blockIdx.x * 4 + wid;

    float4 v = *(const float4*)(feats + (size_t)s * 256 + lane * 4);
    float a0 = v.x, a1 = v.y, a2 = v.z, a3 = v.w;

    float ss = a0 * a0 + a1 * a1 + a2 * a2 + a3 * a3;
    #pragma unroll
    for (int m = 32; m; m >>= 1) ss += __shfl_xor(ss, m);
    float inv = 1.f / fmaxf(sqrtf(ss), 1e-12f);
    a0 *= inv; a1 *= inv; a2 *= inv; a3 *= inv;

    for (int l = 0; l < 7; ++l) {
        #pragma unroll
        for (int q = 0; q < 6; ++q) {
            float cs = angtab[(l * 8 + q) * 2], sn = angtab[(l * 8 + q) * 2 + 1];
            int mask = 32 >> q;
            float sg = (lane & mask) ? sn : -sn;
            float b0 = __shfl_xor(a0, mask), b1v = __shfl_xor(a1, mask);
            float b2v = __shfl_xor(a2, mask), b3v = __shfl_xor(a3, mask);
            a0 = fmaf(sg, b0, cs * a0); a1 = fmaf(sg, b1v, cs * a1);
            a2 = fmaf(sg, b2v, cs * a2); a3 = fmaf(sg, b3v, cs * a3);
        }
        {
            float cs = angtab[(l * 8 + 6) * 2], sn = angtab[(l * 8 + 6) * 2 + 1];
            float n0 = cs * a0 - sn * a2, n2 = fmaf(sn, a0, cs * a2);
            float n1 = cs * a1 - sn * a3, n3 = fmaf(sn, a1, cs * a3);
            a0 = n0; a1 = n1; a2 = n2; a3 = n3;
        }
        {
            float cs = angtab[(l * 8 + 7) * 2], sn = angtab[(l * 8 + 7) * 2 + 1];
            float n0 = cs * a0 - sn * a1, n1 = fmaf(sn, a0, cs * a1);
            float n2 = cs * a2 - sn * a3, n3 = fmaf(sn, a2, cs * a3);
            a0 = n0; a1 = n1; a2 = n2; a3 = n3;
        }
        #pragma unroll
        for (int q = 0; q < 5; ++q) {
            int cmask = 32 >> q, tmask = 16 >> q;
            int src = (lane & cmask) ? (lane ^ tmask) : lane;
            a0 = __shfl(a0, src); a1 = __shfl(a1, src);
            a2 = __shfl(a2, src); a3 = __shfl(a3, src);
        }
        {
            bool f = (lane & 1);
            float n0 = f ? a2 : a0, n2 = f ? a0 : a2;
            float n1 = f ? a3 : a1, n3 = f ? a1 : a3;
            a0 = n0; a1 = n1; a2 = n2; a3 = n3;
        }
        { float t = a2; a2 = a3; a3 = t; }
    }

    float part = a0 * a0 + a1 * a1 + a2 * a2 + a3 * a3;
    part = (lane & 32) ? -part : part;
    #pragma unroll
    for (int m = 32; m; m >>= 1) part += __shfl_xor(part, m);
    float q = part;

    float z = fmaxf(fmaf(q, w1[lane], b1[lane]), 0.f);
    z = fmaf(z - cm[lane], cg[lane] * rsqrtf(cv[lane] + 1e-5f), cb[lane]);
    {
        int j = lane & 31, hb = lane & 32;
        float acc = 0.f;
        #pragma unroll
        for (int t = 0; t < 32; ++t)
            acc = fmaf(w2[j * 64 + hb + t], __shfl(z, hb + t), acc);
        acc += __shfl_xor(acc, 32);
        z = fmaxf(acc + b2[j], 0.f);
    }
    {
        int j3 = lane & 15, qh = (lane >> 4) & 3;
        float p = 0.f;
        #pragma unroll
        for (int t = 0; t < 8; ++t)
            p = fmaf(w3[j3 * 32 + 8 * qh + t], __shfl(z, 8 * qh + t), p);
        p += __shfl_xor(p, 16);
        p += __shfl_xor(p, 32);
        z = fmaxf(p + b3[j3], 0.f);
    }
    {
        float t4 = w4[lane & 15] * z;
        t4 += __shfl_xor(t4, 1); t4 += __shfl_xor(t4, 2);
        t4 += __shfl_xor(t4, 4); t4 += __shfl_xor(t4, 8);
        float o = t4 + b4[0];
        if (lane == 0) out[s] = 1.f / (1.f + expf(-o));
    }
}

// ---------------------------------------------------------------------------
extern "C" void kernel_launch(void* const* d_in, const int* in_sizes, int n_in,
                              void* d_out, int out_size, void* d_ws, size_t ws_size,
                              hipStream_t stream)
{
    const float* x    = (const float*)d_in[0];
    const float* c1w  = (const float*)d_in[1];
    const float* c1b  = (const float*)d_in[2];
    const float* bn1g = (const float*)d_in[3];
    const float* bn1b = (const float*)d_in[4];
    const float* bn1m = (const float*)d_in[5];
    const float* bn1v = (const float*)d_in[6];
    const float* c2w  = (const float*)d_in[7];
    const float* c2b  = (const float*)d_in[8];
    const float* bn2g = (const float*)d_in[9];
    const float* bn2b = (const float*)d_in[10];
    const float* bn2m = (const float*)d_in[11];
    const float* bn2v = (const float*)d_in[12];
    const float* c3w  = (const float*)d_in[13];
    const float* c3b  = (const float*)d_in[14];
    const float* bn3g = (const float*)d_in[15];
    const float* bn3b = (const float*)d_in[16];
    const float* bn3m = (const float*)d_in[17];
    const float* bn3v = (const float*)d_in[18];
    const float* f1w  = (const float*)d_in[19];
    const float* f1b  = (const float*)d_in[20];
    const float* f2w  = (const float*)d_in[21];
    const float* f2b  = (const float*)d_in[22];
    const float* qw   = (const float*)d_in[23];
    const float* w1   = (const float*)d_in[24];
    const float* b1   = (const float*)d_in[25];
    const float* cg   = (const float*)d_in[26];
    const float* cb   = (const float*)d_in[27];
    const float* cm   = (const float*)d_in[28];
    const float* cv   = (const float*)d_in[29];
    const float* w2   = (const float*)d_in[30];
    const float* b2   = (const float*)d_in[31];
    const float* w3   = (const float*)d_in[32];
    const float* b3   = (const float*)d_in[33];
    const float* w4   = (const float*)d_in[34];
    const float* b4   = (const float*)d_in[35];

    unsigned short* ws = (unsigned short*)d_ws;
    unsigned short* pooled_bf = ws;                              // 8192*512 ush
    unsigned short* a1_bf     = pooled_bf + (size_t)BATCH * 512; // 8192*384 ush
    float*          a2        = (float*)(a1_bf + (size_t)BATCH * 384); // 8192*256 f32
    unsigned short* cpack     = (unsigned short*)(a2 + (size_t)BATCH * 256);
    unsigned short* fpack1    = cpack + CPACK_TOTAL;
    unsigned short* fpack2    = fpack1 + FC1_TOTAL;
    float*          angtab    = (float*)(fpack2 + FC2_TOTAL);

    prepack_kernel<<<(PREP_TOTAL + 255) / 256, 256, 0, stream>>>(
        c1w, c2w, c3w, f1w, f2w, qw, cpack, fpack1, fpack2, angtab);

    fused_cnn_mfma<<<BATCH, 256, 0, stream>>>(
        x, c1b, bn1g, bn1b, bn1m, bn1v,
        c2b, bn2g, bn2b, bn2m, bn2v,
        c3b, bn3g, bn3b, bn3m, bn3v, cpack, pooled_bf);

    dim3 g1(BATCH / 128, 384 / 64);
    fc_mfma<1><<<g1, 256, 0, stream>>>(pooled_bf, fpack1, f1b, a1_bf, 384, 512);

    dim3 g2(BATCH / 128, 256 / 64);
    fc_mfma<0><<<g2, 256, 0, stream>>>(a1_bf, fpack2, f2b, a2, 256, 384);

    qsim_tail_kernel<<<BATCH / 4, 256, 0, stream>>>(
        a2, angtab, w1, b1, cg, cb, cm, cv, w2, b2, w3, b3, w4, b4, (float*)d_out);
}

// Round 6
// 141.639 us; speedup vs baseline: 13.1863x; 1.0700x over previous
//
#include <hip/hip_runtime.h>
#include <hip/hip_bf16.h>
#include <math.h>

#define BATCH 8192

typedef __attribute__((ext_vector_type(8))) short bf16x8;
typedef __attribute__((ext_vector_type(4))) float f32x4;
typedef __attribute__((ext_vector_type(16))) float f32x16;

__device__ __forceinline__ unsigned short f2bf(float f) {
    unsigned int u = __builtin_bit_cast(unsigned int, f);
    u = (u + 0x7FFFu + ((u >> 16) & 1u)) >> 16;
    return (unsigned short)u;
}
__device__ __forceinline__ float bf2f(unsigned short h) {
    unsigned int u = ((unsigned int)h) << 16;
    return __builtin_bit_cast(float, u);
}
// HW packed convert (RNE), 1 VALU op for 2 values
__device__ __forceinline__ unsigned int cvtpk(float a, float b) {
    unsigned int r;
    asm("v_cvt_pk_bf16_f32 %0, %1, %2" : "=v"(r) : "v"(a), "v"(b));
    return r;
}
// bank-spreading swizzle at uint4 granularity: XOR bits 3-4 into bits 1-2
__device__ __forceinline__ int swz(int i) { return i ^ (((i >> 3) & 3) << 1); }

// ---- conv weight fragment pack (ushorts) ----
// W1: 4 frags [sel][hl], used as MFMA *A* operand: row=oc(0..7; 8-15 zero),
//     sel0: k=ky*8+kx (ky<4,kx<5). sel1: k=kx (ky=4).
// W2: 6 frags [ky][hl], A operand: row=oc(16), k=(kx<<3)|ic, kx<3 valid.
// W3: 18 frags [ky][kx][hl], 32x32 B operand: col=lane&31=oc, k=8*(lane>>5)+j=ic.
#define W1OFF 0
#define W1FRAGS 4
#define W2OFF (W1OFF + W1FRAGS * 512)
#define W2FRAGS 6
#define W3OFF (W2OFF + W2FRAGS * 512)
#define W3FRAGS 18
#define CPACK_TOTAL (W3OFF + W3FRAGS * 512)
#define FC1_FRAGS (24 * 16 * 2)
#define FC2_FRAGS (16 * 12 * 2)
#define FC1_TOTAL (FC1_FRAGS * 512)
#define FC2_TOTAL (FC2_FRAGS * 512)
#define ANG_TOTAL 112
#define PREP_TOTAL (CPACK_TOTAL + FC1_TOTAL + FC2_TOTAL + ANG_TOTAL)

// ---------------------------------------------------------------------------
__global__ __launch_bounds__(256) void prepack_kernel(
    const float* __restrict__ c1w, const float* __restrict__ c2w,
    const float* __restrict__ c3w, const float* __restrict__ f1w,
    const float* __restrict__ f2w, const float* __restrict__ qw,
    unsigned short* __restrict__ cpack, unsigned short* __restrict__ fpack1,
    unsigned short* __restrict__ fpack2, float* __restrict__ angtab)
{
    int e = blockIdx.x * 256 + threadIdx.x;
    if (e >= PREP_TOTAL) return;

    if (e < CPACK_TOTAL) {
        int f = e >> 9, r = e & 511;
        int l = r >> 3, j = r & 7;
        float w = 0.f; int hl = 0;
        if (f < W1FRAGS) {
            int sel = f >> 1; hl = f & 1;
            int oc = l & 15;
            int k = 8 * (l >> 4) + j;
            int ky, kx;
            if (sel == 0) { ky = k >> 3; kx = k & 7; }
            else          { ky = 4;      kx = k; }
            if (kx < 5 && ky < 5 && oc < 8) w = c1w[oc * 25 + ky * 5 + kx];
        } else if (f < W1FRAGS + W2FRAGS) {
            int f2 = f - W1FRAGS;
            int ky = f2 >> 1; hl = f2 & 1;
            int k = 8 * (l >> 4) + j;
            int kx = k >> 3, ic = k & 7, oc = l & 15;
            if (kx < 3) w = c2w[((oc * 8 + ic) * 3 + ky) * 3 + kx];
        } else {
            int f3 = f - W1FRAGS - W2FRAGS;      // (ky*3+kx)*2+hl
            int ky = f3 / 6, kx = (f3 / 2) % 3; hl = f3 & 1;
            int oc = l & 31, ic = 8 * (l >> 5) + j;
            w = c3w[((oc * 16 + ic) * 3 + ky) * 3 + kx];
        }
        unsigned short hv = f2bf(w);
        unsigned short lv = f2bf(w - bf2f(hv));
        cpack[e] = hl ? lv : hv;
        return;
    }
    e -= CPACK_TOTAL;
    if (e < FC1_TOTAL) {
        int phi = e >> 9, r = e & 511;
        int l = r >> 3, j = r & 7;
        int hl = phi & 1, ks = (phi >> 1) & 15, nb = phi >> 5;
        int n = nb * 16 + (l & 15);
        int kg = ks * 32 + 8 * (l >> 4) + j;
        float w = f1w[n * 512 + kg];
        unsigned short hv = f2bf(w);
        unsigned short lv = f2bf(w - bf2f(hv));
        fpack1[e] = hl ? lv : hv;
        return;
    }
    e -= FC1_TOTAL;
    if (e < FC2_TOTAL) {
        int phi = e >> 9, r = e & 511;
        int l = r >> 3, j = r & 7;
        int hl = phi & 1, ks = (phi >> 1) % 12, nb = phi / 24;
        int n = nb * 16 + (l & 15);
        int kg = ks * 32 + 8 * (l >> 4) + j;
        float w = f2w[n * 384 + kg];
        unsigned short hv = f2bf(w);
        unsigned short lv = f2bf(w - bf2f(hv));
        fpack2[e] = hl ? lv : hv;
        return;
    }
    e -= FC2_TOTAL;
    {
        int a = e >> 1;
        float th = 0.5f * qw[a];
        angtab[e] = (e & 1) ? sinf(th) : cosf(th);
    }
}

// ---------------------------------------------------------------------------
// Fused CNN. One block (4 waves) per sample. 3 barriers.
// LDS: h1p [34*34 swz] uint4 (pixel = 8ch bf16);
//      sbuf = xp 68 rows x 40 dwords | h2p [18*18][2] uint4 swz.
// ---------------------------------------------------------------------------
__global__ __launch_bounds__(256) void fused_cnn_mfma(
    const float* __restrict__ x,
    const float* __restrict__ c1b,
    const float* __restrict__ bn1g, const float* __restrict__ bn1b,
    const float* __restrict__ bn1m, const float* __restrict__ bn1v,
    const float* __restrict__ c2b,
    const float* __restrict__ bn2g, const float* __restrict__ bn2b,
    const float* __restrict__ bn2m, const float* __restrict__ bn2v,
    const float* __restrict__ c3b,
    const float* __restrict__ bn3g, const float* __restrict__ bn3b,
    const float* __restrict__ bn3m, const float* __restrict__ bn3v,
    const unsigned short* __restrict__ cpack,
    unsigned short* __restrict__ pooled_bf)
{
    __shared__ __align__(16) uint4 h1p4[1160];          // 34*34 px + swz pad
    __shared__ __align__(16) unsigned int sd[2720];     // xp 68x40 dw / h2p 656 uint4

    uint4* sbuf4 = (uint4*)sd;

    const int tid = threadIdx.x;
    const int lane = tid & 63;
    const int wv = tid >> 6;
    const int n = blockIdx.x;
    const int lrow = lane & 15;
    const int lq = lane >> 4;         // 0..3

    // ---- P0: stage x interior (bf16) + zero xp pads + zero h1p ring ----
    {
        const float4* xv = (const float4*)(x + (size_t)n * 4096);
        #pragma unroll
        for (int i = 0; i < 4; ++i) {
            int idx = tid + 256 * i;
            float4 v = xv[idx];
            int px = idx * 4;
            int y = px >> 6, xc = px & 63;
            int d = (y + 2) * 40 + (xc >> 1) + 1;
            sd[d]     = cvtpk(v.x, v.y);
            sd[d + 1] = cvtpk(v.z, v.w);
        }
        if (tid < 68)       { int r = tid / 34, c = tid % 34; sd[r * 40 + c] = 0u; }
        else if (tid < 136) { int u = tid - 68; int r = 66 + u / 34, c = u % 34; sd[r * 40 + c] = 0u; }
        if (tid < 128) { int r = 2 + (tid & 63); sd[r * 40 + ((tid >> 6) ? 33 : 0)] = 0u; }
        if (tid < 132) {
            int p;
            if (tid < 34) p = tid;
            else if (tid < 68) p = 33 * 34 + (tid - 34);
            else { int r = 1 + ((tid - 68) & 31); int side = (tid - 68) >> 5; p = r * 34 + side * 33; }
            h1p4[swz(p)] = (uint4){0u, 0u, 0u, 0u};
        }
    }
    __syncthreads();   // B1

    // ---- conv1 (swapped): A=weights [oc][k], B=pixels [k][pix]. C=[oc][pix].
    // Lane: pix=lrow (ox=16h+lrow), regs r -> oc=4*lq+r (lq<2 write).
    {
        bf16x8 wf[4];
        #pragma unroll
        for (int fi = 0; fi < 4; ++fi)
            wf[fi] = __builtin_bit_cast(bf16x8, *(const uint4*)(cpack + W1OFF + fi * 512 + lane * 8));
        float s1v[4], sh1v[4];
        #pragma unroll
        for (int r = 0; r < 4; ++r) {
            int oc = (4 * lq + r) & 7;
            s1v[r] = bn1g[oc] * rsqrtf(bn1v[oc] + 1e-5f);
            sh1v[r] = (c1b[oc] - bn1m[oc]) * s1v[r] + bn1b[oc];
        }
        #pragma unroll 4
        for (int t = 0; t < 16; ++t) {
            int oy = wv * 8 + (t >> 1), h = t & 1;
            // B frag0: ky=lq row, 8-tap window at col 2*(16h+lrow) (ush) -> 3 dwords
            int a1 = (2 * oy + lq) * 40 + 16 * h + lrow;
            uint4 d1; d1.x = sd[a1]; d1.y = sd[a1 + 1]; d1.z = sd[a1 + 2]; d1.w = 0u;
            // B frag1: ky=4 row, lq-invariant (broadcast)
            int a2 = (2 * oy + 4) * 40 + 16 * h + lrow;
            uint4 d2; d2.x = sd[a2]; d2.y = sd[a2 + 1]; d2.z = sd[a2 + 2]; d2.w = 0u;
            f32x4 acc = {0.f, 0.f, 0.f, 0.f};
            acc = __builtin_amdgcn_mfma_f32_16x16x32_bf16(wf[0], __builtin_bit_cast(bf16x8, d1), acc, 0, 0, 0);
            acc = __builtin_amdgcn_mfma_f32_16x16x32_bf16(wf[1], __builtin_bit_cast(bf16x8, d1), acc, 0, 0, 0);
            acc = __builtin_amdgcn_mfma_f32_16x16x32_bf16(wf[2], __builtin_bit_cast(bf16x8, d2), acc, 0, 0, 0);
            acc = __builtin_amdgcn_mfma_f32_16x16x32_bf16(wf[3], __builtin_bit_cast(bf16x8, d2), acc, 0, 0, 0);
            if (lq < 2) {
                unsigned int u0 = cvtpk(fmaxf(fmaf(acc[0], s1v[0], sh1v[0]), 0.f),
                                        fmaxf(fmaf(acc[1], s1v[1], sh1v[1]), 0.f));
                unsigned int u1 = cvtpk(fmaxf(fmaf(acc[2], s1v[2], sh1v[2]), 0.f),
                                        fmaxf(fmaf(acc[3], s1v[3], sh1v[3]), 0.f));
                int p = (oy + 1) * 34 + 16 * h + lrow + 1;
                uint2 wr; wr.x = u0; wr.y = u1;
                *(uint2*)((char*)h1p4 + swz(p) * 16 + 8 * lq) = wr;   // oc 4lq..4lq+3
            }
        }
    }
    __syncthreads();   // B2

    // ---- P2: zero h2p ring + conv2 (swapped). C=[oc][pix], pix=lrow=ox of row oy.
    {
        if (tid < 136) {
            int pp = tid >> 1, half = tid & 1;
            int p;
            if (pp < 18) p = pp;
            else if (pp < 36) p = 17 * 18 + (pp - 18);
            else { int r = 1 + ((pp - 36) & 15); int side = (pp - 36) >> 4; p = r * 18 + side * 17; }
            sbuf4[swz(2 * p + half)] = (uint4){0u, 0u, 0u, 0u};
        }
        bf16x8 w2f[3][2];
        #pragma unroll
        for (int ky = 0; ky < 3; ++ky)
            #pragma unroll
            for (int hl = 0; hl < 2; ++hl)
                w2f[ky][hl] = __builtin_bit_cast(bf16x8,
                    *(const uint4*)(cpack + W2OFF + (ky * 2 + hl) * 512 + lane * 8));
        float s2v[4], sh2v[4];
        #pragma unroll
        for (int r = 0; r < 4; ++r) {
            int oc = 4 * lq + r;
            s2v[r] = bn2g[oc] * rsqrtf(bn2v[oc] + 1e-5f);
            sh2v[r] = (c2b[oc] - bn2m[oc]) * s2v[r] + bn2b[oc];
        }
        int lqe = (lq == 3) ? 0 : lq;      // kx=3 k-slots are zero-weight
        #pragma unroll
        for (int t = 0; t < 4; ++t) {
            int oy = 4 * wv + t;
            f32x4 acc = {0.f, 0.f, 0.f, 0.f};
            #pragma unroll
            for (int ky = 0; ky < 3; ++ky) {
                int iy = 2 * oy + ky;
                int p = iy * 34 + 2 * lrow + lqe;       // B: pix=lrow, kx=lq
                bf16x8 b = __builtin_bit_cast(bf16x8, h1p4[swz(p)]);
                acc = __builtin_amdgcn_mfma_f32_16x16x32_bf16(w2f[ky][0], b, acc, 0, 0, 0);
                acc = __builtin_amdgcn_mfma_f32_16x16x32_bf16(w2f[ky][1], b, acc, 0, 0, 0);
            }
            unsigned int u0 = cvtpk(fmaxf(fmaf(acc[0], s2v[0], sh2v[0]), 0.f),
                                    fmaxf(fmaf(acc[1], s2v[1], sh2v[1]), 0.f));
            unsigned int u1 = cvtpk(fmaxf(fmaf(acc[2], s2v[2], sh2v[2]), 0.f),
                                    fmaxf(fmaf(acc[3], s2v[3], sh2v[3]), 0.f));
            int p = (oy + 1) * 18 + lrow + 1;
            uint2 wr; wr.x = u0; wr.y = u1;
            // oc = 4lq+r -> half = lq>>1, byte-in-half = 8*(lq&1)
            *(uint2*)((char*)sbuf4 + swz(2 * p + (lq >> 1)) * 16 + 8 * (lq & 1)) = wr;
        }
    }
    __syncthreads();   // B3

    // ---- conv3: 16->32ch 3x3 s1 p1 (32x32x16 MFMA) + BN/ReLU + 4x4 pool ----
    {
        f32x16 accA = {0.f}, accB = {0.f};
        const int row = lane & 31;
        const int khalf = lane >> 5;
        #pragma unroll
        for (int ky = 0; ky < 3; ++ky)
            #pragma unroll
            for (int kx = 0; kx < 3; ++kx) {
                int fb = (ky * 3 + kx) * 2;
                bf16x8 bh = __builtin_bit_cast(bf16x8, *(const uint4*)(cpack + W3OFF + fb * 512 + lane * 8));
                bf16x8 bl = __builtin_bit_cast(bf16x8, *(const uint4*)(cpack + W3OFF + (fb + 1) * 512 + lane * 8));
                {
                    int pix = (4 * wv + 0 + (row >> 4) + ky) * 18 + (row & 15) + kx;
                    bf16x8 a = __builtin_bit_cast(bf16x8, sbuf4[swz(2 * pix + khalf)]);
                    accA = __builtin_amdgcn_mfma_f32_32x32x16_bf16(a, bh, accA, 0, 0, 0);
                    accA = __builtin_amdgcn_mfma_f32_32x32x16_bf16(a, bl, accA, 0, 0, 0);
                }
                {
                    int pix = (4 * wv + 2 + (row >> 4) + ky) * 18 + (row & 15) + kx;
                    bf16x8 a = __builtin_bit_cast(bf16x8, sbuf4[swz(2 * pix + khalf)]);
                    accB = __builtin_amdgcn_mfma_f32_32x32x16_bf16(a, bh, accB, 0, 0, 0);
                    accB = __builtin_amdgcn_mfma_f32_32x32x16_bf16(a, bl, accB, 0, 0, 0);
                }
            }
        int oc = lane & 31;
        float s3 = bn3g[oc] * rsqrtf(bn3v[oc] + 1e-5f);
        float sh3 = (c3b[oc] - bn3m[oc]) * s3 + bn3b[oc];
        float pool0 = 0.f, pool1 = 0.f;
        #pragma unroll
        for (int r = 0; r < 16; ++r) {
            float va = fmaxf(fmaf(accA[r], s3, sh3), 0.f);
            float vb = fmaxf(fmaf(accB[r], s3, sh3), 0.f);
            if (((r >> 2) & 1) == 0) { pool0 += va + vb; } else { pool1 += va + vb; }
        }
        int base = n * 512 + oc * 16 + wv * 4 + khalf;
        pooled_bf[base]     = (unsigned short)cvtpk(pool0 * (1.f / 16.f), 0.f);
        pooled_bf[base + 2] = (unsigned short)cvtpk(pool1 * (1.f / 16.f), 0.f);
    }
}

// ---------------------------------------------------------------------------
// FC GEMM (bf16 MFMA): out = relu(A @ W^T + bias). 128x64 tile, BK=64, 4 waves.
// ---------------------------------------------------------------------------
template <int OUT_BF16>
__global__ __launch_bounds__(256) void fc_mfma(
    const unsigned short* __restrict__ Abf,
    const unsigned short* __restrict__ wfrag,
    const float* __restrict__ bias, void* __restrict__ out,
    int N, int K)
{
    __shared__ __align__(16) unsigned short As[8192];
    const int tid = threadIdx.x;
    const int lane = tid & 63;
    const int wv = tid >> 6;
    const int wm = wv >> 1, wn = wv & 1;
    const int bm = blockIdx.x * 128;
    const int bn = blockIdx.y * 64;
    const int lq = lane >> 4;
    const int lr = lane & 15;
    const int KS = K >> 5;

    f32x4 acc[4][2];
    #pragma unroll
    for (int i = 0; i < 4; ++i) { acc[i][0] = (f32x4){0,0,0,0}; acc[i][1] = (f32x4){0,0,0,0}; }

    for (int k0 = 0; k0 < K; k0 += 64) {
        #pragma unroll
        for (int i = 0; i < 4; ++i) {
            int q = tid * 4 + i;
            int row = q >> 3, kc = q & 7;
            uint4 v = *(const uint4*)(Abf + (size_t)(bm + row) * K + k0 + 8 * kc);
            int byte = (row * 128 + 16 * kc) ^ ((row & 7) << 4);
            *(uint4*)((char*)As + byte) = v;
        }
        __syncthreads();
        #pragma unroll
        for (int kk = 0; kk < 2; ++kk) {
            bf16x8 af[4];
            #pragma unroll
            for (int mf = 0; mf < 4; ++mf) {
                int ml = wm * 64 + mf * 16 + lr;
                int byte = (ml * 128 + 64 * kk + 16 * lq) ^ ((ml & 7) << 4);
                af[mf] = __builtin_bit_cast(bf16x8, *(const uint4*)((char*)As + byte));
            }
            int ks = (k0 >> 5) + kk;
            #pragma unroll
            for (int nf = 0; nf < 2; ++nf) {
                int nb = (bn >> 4) + wn * 2 + nf;
                const unsigned short* fb = wfrag + ((size_t)(nb * KS + ks) * 2) * 512 + lane * 8;
                bf16x8 bh = __builtin_bit_cast(bf16x8, *(const uint4*)fb);
                bf16x8 bl = __builtin_bit_cast(bf16x8, *(const uint4*)(fb + 512));
                #pragma unroll
                for (int mf = 0; mf < 4; ++mf) {
                    acc[mf][nf] = __builtin_amdgcn_mfma_f32_16x16x32_bf16(af[mf], bh, acc[mf][nf], 0, 0, 0);
                    acc[mf][nf] = __builtin_amdgcn_mfma_f32_16x16x32_bf16(af[mf], bl, acc[mf][nf], 0, 0, 0);
                }
            }
        }
        __syncthreads();
    }

    #pragma unroll
    for (int nf = 0; nf < 2; ++nf) {
        int nn = bn + wn * 32 + nf * 16 + lr;
        float bv = bias[nn];
        #pragma unroll
        for (int mf = 0; mf < 4; ++mf)
            #pragma unroll
            for (int r = 0; r < 4; ++r) {
                int m = bm + wm * 64 + mf * 16 + 4 * lq + r;
                float v = fmaxf(acc[mf][nf][r] + bv, 0.f);
                if (OUT_BF16) ((unsigned short*)out)[(size_t)m * N + nn] = (unsigned short)cvtpk(v, 0.f);
                else          ((float*)out)[(size_t)m * N + nn] = v;
            }
    }
}

// ---------------------------------------------------------------------------
// L2-norm + 8-qubit/7-layer qsim + fused tail MLP. One wave per sample.
// ---------------------------------------------------------------------------
__global__ __launch_bounds__(256) void qsim_tail_kernel(
    const float* __restrict__ feats, const float* __restrict__ angtab,
    const float* __restrict__ w1, const float* __restrict__ b1,
    const float* __restrict__ cg, const float* __restrict__ cb,
    const float* __restrict__ cm, const float* __restrict__ cv,
    const float* __restrict__ w2, const float* __restrict__ b2,
    const float* __restrict__ w3, const float* __restrict__ b3,
    const float* __restrict__ w4, const float* __restrict__ b4,
    float* __restrict__ out)
{
    const int lane = threadIdx.x & 63;
    const int wid = threadIdx.x >> 6;
    const int s = blockIdx.x * 4 + wid;

    float4 v = *(const float4*)(feats + (size_t)s * 256 + lane * 4);
    float a0 = v.x, a1 = v.y, a2 = v.z, a3 = v.w;

    float ss = a0 * a0 + a1 * a1 + a2 * a2 + a3 * a3;
    #pragma unroll
    for (int m = 32; m; m >>= 1) ss += __shfl_xor(ss, m);
    float inv = 1.f / fmaxf(sqrtf(ss), 1e-12f);
    a0 *= inv; a1 *= inv; a2 *= inv; a3 *= inv;

    // composed 5-CNOT lane permutation: bit_k ^= bit_{k+1} (k=0..4)
    const int csrc = lane ^ ((lane >> 1) & 31);

    for (int l = 0; l < 7; ++l) {
        #pragma unroll
        for (int q = 0; q < 6; ++q) {
            float cs = angtab[(l * 8 + q) * 2], sn = angtab[(l * 8 + q) * 2 + 1];
            int mask = 32 >> q;
            float sg = (lane & mask) ? sn : -sn;
            float b0 = __shfl_xor(a0, mask), b1v = __shfl_xor(a1, mask);
            float b2v = __shfl_xor(a2, mask), b3v = __shfl_xor(a3, mask);
            a0 = fmaf(sg, b0, cs * a0); a1 = fmaf(sg, b1v, cs * a1);
            a2 = fmaf(sg, b2v, cs * a2); a3 = fmaf(sg, b3v, cs * a3);
        }
        {
            float cs = angtab[(l * 8 + 6) * 2], sn = angtab[(l * 8 + 6) * 2 + 1];
            float n0 = cs * a0 - sn * a2, n2 = fmaf(sn, a0, cs * a2);
            float n1 = cs * a1 - sn * a3, n3 = fmaf(sn, a1, cs * a3);
            a0 = n0; a1 = n1; a2 = n2; a3 = n3;
        }
        {
            float cs = angtab[(l * 8 + 7) * 2], sn = angtab[(l * 8 + 7) * 2 + 1];
            float n0 = cs * a0 - sn * a1, n1 = fmaf(sn, a0, cs * a1);
            float n2 = cs * a2 - sn * a3, n3 = fmaf(sn, a2, cs * a3);
            a0 = n0; a1 = n1; a2 = n2; a3 = n3;
        }
        // CNOT(0,1)..(4,5) composed into one shuffle
        a0 = __shfl(a0, csrc); a1 = __shfl(a1, csrc);
        a2 = __shfl(a2, csrc); a3 = __shfl(a3, csrc);
        // CNOT(5,6): control lane bit0, target reg bit1
        {
            bool f = (lane & 1);
            float n0 = f ? a2 : a0, n2 = f ? a0 : a2;
            float n1 = f ? a3 : a1, n3 = f ? a1 : a3;
            a0 = n0; a1 = n1; a2 = n2; a3 = n3;
        }
        // CNOT(6,7): swap a2<->a3
        { float t = a2; a2 = a3; a3 = t; }
    }

    float part = a0 * a0 + a1 * a1 + a2 * a2 + a3 * a3;
    part = (lane & 32) ? -part : part;
    #pragma unroll
    for (int m = 32; m; m >>= 1) part += __shfl_xor(part, m);
    float q = part;

    float z = fmaxf(fmaf(q, w1[lane], b1[lane]), 0.f);
    z = fmaf(z - cm[lane], cg[lane] * rsqrtf(cv[lane] + 1e-5f), cb[lane]);
    {
        int j = lane & 31, hb = lane & 32;
        float acc = 0.f;
        #pragma unroll
        for (int t = 0; t < 32; ++t)
            acc = fmaf(w2[j * 64 + hb + t], __shfl(z, hb + t), acc);
        acc += __shfl_xor(acc, 32);
        z = fmaxf(acc + b2[j], 0.f);
    }
    {
        int j3 = lane & 15, qh = (lane >> 4) & 3;
        float p = 0.f;
        #pragma unroll
        for (int t = 0; t < 8; ++t)
            p = fmaf(w3[j3 * 32 + 8 * qh + t], __shfl(z, 8 * qh + t), p);
        p += __shfl_xor(p, 16);
        p += __shfl_xor(p, 32);
        z = fmaxf(p + b3[j3], 0.f);
    }
    {
        float t4 = w4[lane & 15] * z;
        t4 += __shfl_xor(t4, 1); t4 += __shfl_xor(t4, 2);
        t4 += __shfl_xor(t4, 4); t4 += __shfl_xor(t4, 8);
        float o = t4 + b4[0];
        if (lane == 0) out[s] = 1.f / (1.f + expf(-o));
    }
}

// ---------------------------------------------------------------------------
extern "C" void kernel_launch(void* const* d_in, const int* in_sizes, int n_in,
                              void* d_out, int out_size, void* d_ws, size_t ws_size,
                              hipStream_t stream)
{
    const float* x    = (const float*)d_in[0];
    const float* c1w  = (const float*)d_in[1];
    const float* c1b  = (const float*)d_in[2];
    const float* bn1g = (const float*)d_in[3];
    const float* bn1b = (const float*)d_in[4];
    const float* bn1m = (const float*)d_in[5];
    const float* bn1v = (const float*)d_in[6];
    const float* c2w  = (const float*)d_in[7];
    const float* c2b  = (const float*)d_in[8];
    const float* bn2g = (const float*)d_in[9];
    const float* bn2b = (const float*)d_in[10];
    const float* bn2m = (const float*)d_in[11];
    const float* bn2v = (const float*)d_in[12];
    const float* c3w  = (const float*)d_in[13];
    const float* c3b  = (const float*)d_in[14];
    const float* bn3g = (const float*)d_in[15];
    const float* bn3b = (const float*)d_in[16];
    const float* bn3m = (const float*)d_in[17];
    const float* bn3v = (const float*)d_in[18];
    const float* f1w  = (const float*)d_in[19];
    const float* f1b  = (const float*)d_in[20];
    const float* f2w  = (const float*)d_in[21];
    const float* f2b  = (const float*)d_in[22];
    const float* qw   = (const float*)d_in[23];
    const float* w1   = (const float*)d_in[24];
    const float* b1   = (const float*)d_in[25];
    const float* cg   = (const float*)d_in[26];
    const float* cb   = (const float*)d_in[27];
    const float* cm   = (const float*)d_in[28];
    const float* cv   = (const float*)d_in[29];
    const float* w2   = (const float*)d_in[30];
    const float* b2   = (const float*)d_in[31];
    const float* w3   = (const float*)d_in[32];
    const float* b3   = (const float*)d_in[33];
    const float* w4   = (const float*)d_in[34];
    const float* b4   = (const float*)d_in[35];

    unsigned short* ws = (unsigned short*)d_ws;
    unsigned short* pooled_bf = ws;                              // 8192*512 ush
    unsigned short* a1_bf     = pooled_bf + (size_t)BATCH * 512; // 8192*384 ush
    float*          a2        = (float*)(a1_bf + (size_t)BATCH * 384); // 8192*256 f32
    unsigned short* cpack     = (unsigned short*)(a2 + (size_t)BATCH * 256);
    unsigned short* fpack1    = cpack + CPACK_TOTAL;
    unsigned short* fpack2    = fpack1 + FC1_TOTAL;
    float*          angtab    = (float*)(fpack2 + FC2_TOTAL);

    prepack_kernel<<<(PREP_TOTAL + 255) / 256, 256, 0, stream>>>(
        c1w, c2w, c3w, f1w, f2w, qw, cpack, fpack1, fpack2, angtab);

    fused_cnn_mfma<<<BATCH, 256, 0, stream>>>(
        x, c1b, bn1g, bn1b, bn1m, bn1v,
        c2b, bn2g, bn2b, bn2m, bn2v,
        c3b, bn3g, bn3b, bn3m, bn3v, cpack, pooled_bf);

    dim3 g1(BATCH / 128, 384 / 64);
    fc_mfma<1><<<g1, 256, 0, stream>>>(pooled_bf, fpack1, f1b, a1_bf, 384, 512);

    dim3 g2(BATCH / 128, 256 / 64);
    fc_mfma<0><<<g2, 256, 0, stream>>>(a1_bf, fpack2, f2b, a2, 256, 384);

    qsim_tail_kernel<<<BATCH / 4, 256, 0, stream>>>(
        a2, angtab, w1, b1, cg, cb, cm, cv, w2, b2, w3, b3, w4, b4, (float*)d_out);
}

// Round 7
// 141.352 us; speedup vs baseline: 13.2131x; 1.0020x over previous
//
#include <hip/hip_runtime.h>
#include <hip/hip_bf16.h>
#include <math.h>

#define BATCH 8192

typedef __attribute__((ext_vector_type(8))) short bf16x8;
typedef __attribute__((ext_vector_type(4))) float f32x4;
typedef __attribute__((ext_vector_type(16))) float f32x16;

__device__ __forceinline__ unsigned short f2bf(float f) {
    unsigned int u = __builtin_bit_cast(unsigned int, f);
    u = (u + 0x7FFFu + ((u >> 16) & 1u)) >> 16;
    return (unsigned short)u;
}
__device__ __forceinline__ float bf2f(unsigned short h) {
    unsigned int u = ((unsigned int)h) << 16;
    return __builtin_bit_cast(float, u);
}
// HW packed convert (RNE), 1 VALU op for 2 values
__device__ __forceinline__ unsigned int cvtpk(float a, float b) {
    unsigned int r;
    asm("v_cvt_pk_bf16_f32 %0, %1, %2" : "=v"(r) : "v"(a), "v"(b));
    return r;
}
// bank-spreading swizzle at uint4 granularity: XOR bits 3-4 into bits 0-1.
// Even-stride-2 access patterns (2*pix+c) hit all 8 bank-groups exactly 2x.
__device__ __forceinline__ int swz(int i) { return i ^ ((i >> 3) & 3); }

// ---- conv weight fragment pack (ushorts) ----
// W1: 4 frags [sel][hl], used as MFMA *A* operand: row=oc(0..7; 8-15 zero),
//     sel0: k=ky*8+kx (ky<4,kx<5). sel1: k=kx (ky=4).
// W2: 6 frags [ky][hl], A operand: row=oc(16), k=(kx<<3)|ic, kx<3 valid.
// W3: 18 frags [ky][kx][hl], 32x32 B operand: col=lane&31=oc, k=8*(lane>>5)+j=ic.
#define W1OFF 0
#define W1FRAGS 4
#define W2OFF (W1OFF + W1FRAGS * 512)
#define W2FRAGS 6
#define W3OFF (W2OFF + W2FRAGS * 512)
#define W3FRAGS 18
#define CPACK_TOTAL (W3OFF + W3FRAGS * 512)
#define FC1_FRAGS (24 * 16 * 2)
#define FC2_FRAGS (16 * 12 * 2)
#define FC1_TOTAL (FC1_FRAGS * 512)
#define FC2_TOTAL (FC2_FRAGS * 512)
#define ANG_TOTAL 112
#define PREP_TOTAL (CPACK_TOTAL + FC1_TOTAL + FC2_TOTAL + ANG_TOTAL)

// ---------------------------------------------------------------------------
__global__ __launch_bounds__(256) void prepack_kernel(
    const float* __restrict__ c1w, const float* __restrict__ c2w,
    const float* __restrict__ c3w, const float* __restrict__ f1w,
    const float* __restrict__ f2w, const float* __restrict__ qw,
    unsigned short* __restrict__ cpack, unsigned short* __restrict__ fpack1,
    unsigned short* __restrict__ fpack2, float* __restrict__ angtab)
{
    int e = blockIdx.x * 256 + threadIdx.x;
    if (e >= PREP_TOTAL) return;

    if (e < CPACK_TOTAL) {
        int f = e >> 9, r = e & 511;
        int l = r >> 3, j = r & 7;
        float w = 0.f; int hl = 0;
        if (f < W1FRAGS) {
            int sel = f >> 1; hl = f & 1;
            int oc = l & 15;
            int k = 8 * (l >> 4) + j;
            int ky, kx;
            if (sel == 0) { ky = k >> 3; kx = k & 7; }
            else          { ky = 4;      kx = k; }
            if (kx < 5 && ky < 5 && oc < 8) w = c1w[oc * 25 + ky * 5 + kx];
        } else if (f < W1FRAGS + W2FRAGS) {
            int f2 = f - W1FRAGS;
            int ky = f2 >> 1; hl = f2 & 1;
            int k = 8 * (l >> 4) + j;
            int kx = k >> 3, ic = k & 7, oc = l & 15;
            if (kx < 3) w = c2w[((oc * 8 + ic) * 3 + ky) * 3 + kx];
        } else {
            int f3 = f - W1FRAGS - W2FRAGS;      // (ky*3+kx)*2+hl
            int ky = f3 / 6, kx = (f3 / 2) % 3; hl = f3 & 1;
            int oc = l & 31, ic = 8 * (l >> 5) + j;
            w = c3w[((oc * 16 + ic) * 3 + ky) * 3 + kx];
        }
        unsigned short hv = f2bf(w);
        unsigned short lv = f2bf(w - bf2f(hv));
        cpack[e] = hl ? lv : hv;
        return;
    }
    e -= CPACK_TOTAL;
    if (e < FC1_TOTAL) {
        int phi = e >> 9, r = e & 511;
        int l = r >> 3, j = r & 7;
        int hl = phi & 1, ks = (phi >> 1) & 15, nb = phi >> 5;
        int n = nb * 16 + (l & 15);
        int kg = ks * 32 + 8 * (l >> 4) + j;
        float w = f1w[n * 512 + kg];
        unsigned short hv = f2bf(w);
        unsigned short lv = f2bf(w - bf2f(hv));
        fpack1[e] = hl ? lv : hv;
        return;
    }
    e -= FC1_TOTAL;
    if (e < FC2_TOTAL) {
        int phi = e >> 9, r = e & 511;
        int l = r >> 3, j = r & 7;
        int hl = phi & 1, ks = (phi >> 1) % 12, nb = phi / 24;
        int n = nb * 16 + (l & 15);
        int kg = ks * 32 + 8 * (l >> 4) + j;
        float w = f2w[n * 384 + kg];
        unsigned short hv = f2bf(w);
        unsigned short lv = f2bf(w - bf2f(hv));
        fpack2[e] = hl ? lv : hv;
        return;
    }
    e -= FC2_TOTAL;
    {
        int a = e >> 1;
        float th = 0.5f * qw[a];
        angtab[e] = (e & 1) ? sinf(th) : cosf(th);
    }
}

// ---------------------------------------------------------------------------
// Fused CNN. One block (4 waves) per sample. 3 barriers.
// LDS: h1p [34*34 swz] uint4 (pixel = 8ch bf16);
//      sbuf = xp 68 rows x 40 dwords | h2p [18*18][2] uint4 swz.
// ---------------------------------------------------------------------------
__global__ __launch_bounds__(256) void fused_cnn_mfma(
    const float* __restrict__ x,
    const float* __restrict__ c1b,
    const float* __restrict__ bn1g, const float* __restrict__ bn1b,
    const float* __restrict__ bn1m, const float* __restrict__ bn1v,
    const float* __restrict__ c2b,
    const float* __restrict__ bn2g, const float* __restrict__ bn2b,
    const float* __restrict__ bn2m, const float* __restrict__ bn2v,
    const float* __restrict__ c3b,
    const float* __restrict__ bn3g, const float* __restrict__ bn3b,
    const float* __restrict__ bn3m, const float* __restrict__ bn3v,
    const unsigned short* __restrict__ cpack,
    unsigned short* __restrict__ pooled_bf)
{
    __shared__ __align__(16) uint4 h1p4[1160];          // 34*34 px + pad
    __shared__ __align__(16) unsigned int sd[2720];     // xp 68x40 dw / h2p 656 uint4

    uint4* sbuf4 = (uint4*)sd;

    const int tid = threadIdx.x;
    const int lane = tid & 63;
    const int wv = tid >> 6;
    const int n = blockIdx.x;
    const int lrow = lane & 15;
    const int lq = lane >> 4;         // 0..3

    // ---- P0: stage x interior (bf16) + zero xp pads + zero h1p ring ----
    {
        const float4* xv = (const float4*)(x + (size_t)n * 4096);
        #pragma unroll
        for (int i = 0; i < 4; ++i) {
            int idx = tid + 256 * i;
            float4 v = xv[idx];
            int px = idx * 4;
            int y = px >> 6, xc = px & 63;
            int d = (y + 2) * 40 + (xc >> 1) + 1;
            sd[d]     = cvtpk(v.x, v.y);
            sd[d + 1] = cvtpk(v.z, v.w);
        }
        if (tid < 68)       { int r = tid / 34, c = tid % 34; sd[r * 40 + c] = 0u; }
        else if (tid < 136) { int u = tid - 68; int r = 66 + u / 34, c = u % 34; sd[r * 40 + c] = 0u; }
        if (tid < 128) { int r = 2 + (tid & 63); sd[r * 40 + ((tid >> 6) ? 33 : 0)] = 0u; }
        if (tid < 132) {
            int p;
            if (tid < 34) p = tid;
            else if (tid < 68) p = 33 * 34 + (tid - 34);
            else { int r = 1 + ((tid - 68) & 31); int side = (tid - 68) >> 5; p = r * 34 + side * 33; }
            h1p4[swz(p)] = (uint4){0u, 0u, 0u, 0u};
        }
    }
    __syncthreads();   // B1

    // ---- conv1 (swapped): A=weights [oc][k], B=pixels [k][pix]. C=[oc][pix].
    {
        bf16x8 wf[4];
        #pragma unroll
        for (int fi = 0; fi < 4; ++fi)
            wf[fi] = __builtin_bit_cast(bf16x8, *(const uint4*)(cpack + W1OFF + fi * 512 + lane * 8));
        float s1v[4], sh1v[4];
        #pragma unroll
        for (int r = 0; r < 4; ++r) {
            int oc = (4 * lq + r) & 7;
            s1v[r] = bn1g[oc] * rsqrtf(bn1v[oc] + 1e-5f);
            sh1v[r] = (c1b[oc] - bn1m[oc]) * s1v[r] + bn1b[oc];
        }
        #pragma unroll 4
        for (int t = 0; t < 16; ++t) {
            int oy = wv * 8 + (t >> 1), h = t & 1;
            int a1 = (2 * oy + lq) * 40 + 16 * h + lrow;
            uint4 d1; d1.x = sd[a1]; d1.y = sd[a1 + 1]; d1.z = sd[a1 + 2]; d1.w = 0u;
            int a2 = (2 * oy + 4) * 40 + 16 * h + lrow;   // lq-invariant -> broadcast
            uint4 d2; d2.x = sd[a2]; d2.y = sd[a2 + 1]; d2.z = sd[a2 + 2]; d2.w = 0u;
            f32x4 acc = {0.f, 0.f, 0.f, 0.f};
            acc = __builtin_amdgcn_mfma_f32_16x16x32_bf16(wf[0], __builtin_bit_cast(bf16x8, d1), acc, 0, 0, 0);
            acc = __builtin_amdgcn_mfma_f32_16x16x32_bf16(wf[1], __builtin_bit_cast(bf16x8, d1), acc, 0, 0, 0);
            acc = __builtin_amdgcn_mfma_f32_16x16x32_bf16(wf[2], __builtin_bit_cast(bf16x8, d2), acc, 0, 0, 0);
            acc = __builtin_amdgcn_mfma_f32_16x16x32_bf16(wf[3], __builtin_bit_cast(bf16x8, d2), acc, 0, 0, 0);
            if (lq < 2) {
                unsigned int u0 = cvtpk(fmaxf(fmaf(acc[0], s1v[0], sh1v[0]), 0.f),
                                        fmaxf(fmaf(acc[1], s1v[1], sh1v[1]), 0.f));
                unsigned int u1 = cvtpk(fmaxf(fmaf(acc[2], s1v[2], sh1v[2]), 0.f),
                                        fmaxf(fmaf(acc[3], s1v[3], sh1v[3]), 0.f));
                int p = (oy + 1) * 34 + 16 * h + lrow + 1;
                uint2 wr; wr.x = u0; wr.y = u1;
                *(uint2*)((char*)h1p4 + swz(p) * 16 + 8 * lq) = wr;   // oc 4lq..4lq+3
            }
        }
    }
    __syncthreads();   // B2

    // ---- P2: zero h2p ring + conv2 (swapped). C=[oc][pix], pix=lrow=ox of row oy.
    {
        if (tid < 136) {
            int pp = tid >> 1, half = tid & 1;
            int p;
            if (pp < 18) p = pp;
            else if (pp < 36) p = 17 * 18 + (pp - 18);
            else { int r = 1 + ((pp - 36) & 15); int side = (pp - 36) >> 4; p = r * 18 + side * 17; }
            sbuf4[swz(2 * p + half)] = (uint4){0u, 0u, 0u, 0u};
        }
        bf16x8 w2f[3][2];
        #pragma unroll
        for (int ky = 0; ky < 3; ++ky)
            #pragma unroll
            for (int hl = 0; hl < 2; ++hl)
                w2f[ky][hl] = __builtin_bit_cast(bf16x8,
                    *(const uint4*)(cpack + W2OFF + (ky * 2 + hl) * 512 + lane * 8));
        float s2v[4], sh2v[4];
        #pragma unroll
        for (int r = 0; r < 4; ++r) {
            int oc = 4 * lq + r;
            s2v[r] = bn2g[oc] * rsqrtf(bn2v[oc] + 1e-5f);
            sh2v[r] = (c2b[oc] - bn2m[oc]) * s2v[r] + bn2b[oc];
        }
        int lqe = (lq == 3) ? 0 : lq;      // kx=3 k-slots are zero-weight
        #pragma unroll
        for (int t = 0; t < 4; ++t) {
            int oy = 4 * wv + t;
            f32x4 acc = {0.f, 0.f, 0.f, 0.f};
            #pragma unroll
            for (int ky = 0; ky < 3; ++ky) {
                int iy = 2 * oy + ky;
                int p = iy * 34 + 2 * lrow + lqe;       // B: pix=lrow, kx=lq
                bf16x8 b = __builtin_bit_cast(bf16x8, h1p4[swz(p)]);
                acc = __builtin_amdgcn_mfma_f32_16x16x32_bf16(w2f[ky][0], b, acc, 0, 0, 0);
                acc = __builtin_amdgcn_mfma_f32_16x16x32_bf16(w2f[ky][1], b, acc, 0, 0, 0);
            }
            unsigned int u0 = cvtpk(fmaxf(fmaf(acc[0], s2v[0], sh2v[0]), 0.f),
                                    fmaxf(fmaf(acc[1], s2v[1], sh2v[1]), 0.f));
            unsigned int u1 = cvtpk(fmaxf(fmaf(acc[2], s2v[2], sh2v[2]), 0.f),
                                    fmaxf(fmaf(acc[3], s2v[3], sh2v[3]), 0.f));
            int p = (oy + 1) * 18 + lrow + 1;
            uint2 wr; wr.x = u0; wr.y = u1;
            *(uint2*)((char*)sbuf4 + swz(2 * p + (lq >> 1)) * 16 + 8 * (lq & 1)) = wr;
        }
    }
    __syncthreads();   // B3

    // ---- conv3: 16->32ch 3x3 s1 p1 (32x32x16 MFMA) + BN/ReLU + 4x4 pool ----
    {
        f32x16 accA = {0.f}, accB = {0.f};
        const int row = lane & 31;
        const int khalf = lane >> 5;
        #pragma unroll
        for (int ky = 0; ky < 3; ++ky)
            #pragma unroll
            for (int kx = 0; kx < 3; ++kx) {
                int fb = (ky * 3 + kx) * 2;
                bf16x8 bh = __builtin_bit_cast(bf16x8, *(const uint4*)(cpack + W3OFF + fb * 512 + lane * 8));
                bf16x8 bl = __builtin_bit_cast(bf16x8, *(const uint4*)(cpack + W3OFF + (fb + 1) * 512 + lane * 8));
                {
                    int pix = (4 * wv + 0 + (row >> 4) + ky) * 18 + (row & 15) + kx;
                    bf16x8 a = __builtin_bit_cast(bf16x8, sbuf4[swz(2 * pix + khalf)]);
                    accA = __builtin_amdgcn_mfma_f32_32x32x16_bf16(a, bh, accA, 0, 0, 0);
                    accA = __builtin_amdgcn_mfma_f32_32x32x16_bf16(a, bl, accA, 0, 0, 0);
                }
                {
                    int pix = (4 * wv + 2 + (row >> 4) + ky) * 18 + (row & 15) + kx;
                    bf16x8 a = __builtin_bit_cast(bf16x8, sbuf4[swz(2 * pix + khalf)]);
                    accB = __builtin_amdgcn_mfma_f32_32x32x16_bf16(a, bh, accB, 0, 0, 0);
                    accB = __builtin_amdgcn_mfma_f32_32x32x16_bf16(a, bl, accB, 0, 0, 0);
                }
            }
        int oc = lane & 31;
        float s3 = bn3g[oc] * rsqrtf(bn3v[oc] + 1e-5f);
        float sh3 = (c3b[oc] - bn3m[oc]) * s3 + bn3b[oc];
        float pool0 = 0.f, pool1 = 0.f;
        #pragma unroll
        for (int r = 0; r < 16; ++r) {
            float va = fmaxf(fmaf(accA[r], s3, sh3), 0.f);
            float vb = fmaxf(fmaf(accB[r], s3, sh3), 0.f);
            if (((r >> 2) & 1) == 0) { pool0 += va + vb; } else { pool1 += va + vb; }
        }
        int base = n * 512 + oc * 16 + wv * 4 + khalf;
        pooled_bf[base]     = (unsigned short)cvtpk(pool0 * (1.f / 16.f), 0.f);
        pooled_bf[base + 2] = (unsigned short)cvtpk(pool1 * (1.f / 16.f), 0.f);
    }
}

// ---------------------------------------------------------------------------
// FC GEMM (bf16 MFMA): out = relu(A @ W^T + bias). 128x64 tile, BK=64, 4 waves.
// ---------------------------------------------------------------------------
template <int OUT_BF16>
__global__ __launch_bounds__(256) void fc_mfma(
    const unsigned short* __restrict__ Abf,
    const unsigned short* __restrict__ wfrag,
    const float* __restrict__ bias, void* __restrict__ out,
    int N, int K)
{
    __shared__ __align__(16) unsigned short As[8192];
    const int tid = threadIdx.x;
    const int lane = tid & 63;
    const int wv = tid >> 6;
    const int wm = wv >> 1, wn = wv & 1;
    const int bm = blockIdx.x * 128;
    const int bn = blockIdx.y * 64;
    const int lq = lane >> 4;
    const int lr = lane & 15;
    const int KS = K >> 5;

    f32x4 acc[4][2];
    #pragma unroll
    for (int i = 0; i < 4; ++i) { acc[i][0] = (f32x4){0,0,0,0}; acc[i][1] = (f32x4){0,0,0,0}; }

    for (int k0 = 0; k0 < K; k0 += 64) {
        #pragma unroll
        for (int i = 0; i < 4; ++i) {
            int q = tid * 4 + i;
            int row = q >> 3, kc = q & 7;
            uint4 v = *(const uint4*)(Abf + (size_t)(bm + row) * K + k0 + 8 * kc);
            int byte = (row * 128 + 16 * kc) ^ ((row & 7) << 4);
            *(uint4*)((char*)As + byte) = v;
        }
        __syncthreads();
        #pragma unroll
        for (int kk = 0; kk < 2; ++kk) {
            bf16x8 af[4];
            #pragma unroll
            for (int mf = 0; mf < 4; ++mf) {
                int ml = wm * 64 + mf * 16 + lr;
                int byte = (ml * 128 + 64 * kk + 16 * lq) ^ ((ml & 7) << 4);
                af[mf] = __builtin_bit_cast(bf16x8, *(const uint4*)((char*)As + byte));
            }
            int ks = (k0 >> 5) + kk;
            #pragma unroll
            for (int nf = 0; nf < 2; ++nf) {
                int nb = (bn >> 4) + wn * 2 + nf;
                const unsigned short* fb = wfrag + ((size_t)(nb * KS + ks) * 2) * 512 + lane * 8;
                bf16x8 bh = __builtin_bit_cast(bf16x8, *(const uint4*)fb);
                bf16x8 bl = __builtin_bit_cast(bf16x8, *(const uint4*)(fb + 512));
                #pragma unroll
                for (int mf = 0; mf < 4; ++mf) {
                    acc[mf][nf] = __builtin_amdgcn_mfma_f32_16x16x32_bf16(af[mf], bh, acc[mf][nf], 0, 0, 0);
                    acc[mf][nf] = __builtin_amdgcn_mfma_f32_16x16x32_bf16(af[mf], bl, acc[mf][nf], 0, 0, 0);
                }
            }
        }
        __syncthreads();
    }

    #pragma unroll
    for (int nf = 0; nf < 2; ++nf) {
        int nn = bn + wn * 32 + nf * 16 + lr;
        float bv = bias[nn];
        #pragma unroll
        for (int mf = 0; mf < 4; ++mf)
            #pragma unroll
            for (int r = 0; r < 4; ++r) {
                int m = bm + wm * 64 + mf * 16 + 4 * lq + r;
                float v = fmaxf(acc[mf][nf][r] + bv, 0.f);
                if (OUT_BF16) ((unsigned short*)out)[(size_t)m * N + nn] = (unsigned short)cvtpk(v, 0.f);
                else          ((float*)out)[(size_t)m * N + nn] = v;
            }
    }
}

// ---------------------------------------------------------------------------
// L2-norm + 8-qubit/7-layer qsim + fused tail MLP. One wave per sample.
// ---------------------------------------------------------------------------
__global__ __launch_bounds__(256) void qsim_tail_kernel(
    const float* __restrict__ feats, const float* __restrict__ angtab,
    const float* __restrict__ w1, const float* __restrict__ b1,
    const float* __restrict__ cg, const float* __restrict__ cb,
    const float* __restrict__ cm, const float* __restrict__ cv,
    const float* __restrict__ w2, const float* __restrict__ b2,
    const float* __restrict__ w3, const float* __restrict__ b3,
    const float* __restrict__ w4, const float* __restrict__ b4,
    float* __restrict__ out)
{
    const int lane = threadIdx.x & 63;
    const int wid = threadIdx.x >> 6;
    const int s = blockIdx.x * 4 + wid;

    float4 v = *(const float4*)(feats + (size_t)s * 256 + lane * 4);
    float a0 = v.x, a1 = v.y, a2 = v.z, a3 = v.w;

    float ss = a0 * a0 + a1 * a1 + a2 * a2 + a3 * a3;
    #pragma unroll
    for (int m = 32; m; m >>= 1) ss += __shfl_xor(ss, m);
    float inv = 1.f / fmaxf(sqrtf(ss), 1e-12f);
    a0 *= inv; a1 *= inv; a2 *= inv; a3 *= inv;

    // composed 5-CNOT lane permutation: bit_k ^= bit_{k+1} (k=0..4)
    const int csrc = lane ^ ((lane >> 1) & 31);

    for (int l = 0; l < 7; ++l) {
        #pragma unroll
        for (int q = 0; q < 6; ++q) {
            float cs = angtab[(l * 8 + q) * 2], sn = angtab[(l * 8 + q) * 2 + 1];
            int mask = 32 >> q;
            float sg = (lane & mask) ? sn : -sn;
            float b0 = __shfl_xor(a0, mask), b1v = __shfl_xor(a1, mask);
            float b2v = __shfl_xor(a2, mask), b3v = __shfl_xor(a3, mask);
            a0 = fmaf(sg, b0, cs * a0); a1 = fmaf(sg, b1v, cs * a1);
            a2 = fmaf(sg, b2v, cs * a2); a3 = fmaf(sg, b3v, cs * a3);
        }
        {
            float cs = angtab[(l * 8 + 6) * 2], sn = angtab[(l * 8 + 6) * 2 + 1];
            float n0 = cs * a0 - sn * a2, n2 = fmaf(sn, a0, cs * a2);
            float n1 = cs * a1 - sn * a3, n3 = fmaf(sn, a1, cs * a3);
            a0 = n0; a1 = n1; a2 = n2; a3 = n3;
        }
        {
            float cs = angtab[(l * 8 + 7) * 2], sn = angtab[(l * 8 + 7) * 2 + 1];
            float n0 = cs * a0 - sn * a1, n1 = fmaf(sn, a0, cs * a1);
            float n2 = cs * a2 - sn * a3, n3 = fmaf(sn, a2, cs * a3);
            a0 = n0; a1 = n1; a2 = n2; a3 = n3;
        }
        a0 = __shfl(a0, csrc); a1 = __shfl(a1, csrc);
        a2 = __shfl(a2, csrc); a3 = __shfl(a3, csrc);
        {
            bool f = (lane & 1);
            float n0 = f ? a2 : a0, n2 = f ? a0 : a2;
            float n1 = f ? a3 : a1, n3 = f ? a1 : a3;
            a0 = n0; a1 = n1; a2 = n2; a3 = n3;
        }
        { float t = a2; a2 = a3; a3 = t; }
    }

    float part = a0 * a0 + a1 * a1 + a2 * a2 + a3 * a3;
    part = (lane & 32) ? -part : part;
    #pragma unroll
    for (int m = 32; m; m >>= 1) part += __shfl_xor(part, m);
    float q = part;

    float z = fmaxf(fmaf(q, w1[lane], b1[lane]), 0.f);
    z = fmaf(z - cm[lane], cg[lane] * rsqrtf(cv[lane] + 1e-5f), cb[lane]);
    {
        int j = lane & 31, hb = lane & 32;
        float acc = 0.f;
        #pragma unroll
        for (int t = 0; t < 32; ++t)
            acc = fmaf(w2[j * 64 + hb + t], __shfl(z, hb + t), acc);
        acc += __shfl_xor(acc, 32);
        z = fmaxf(acc + b2[j], 0.f);
    }
    {
        int j3 = lane & 15, qh = (lane >> 4) & 3;
        float p = 0.f;
        #pragma unroll
        for (int t = 0; t < 8; ++t)
            p = fmaf(w3[j3 * 32 + 8 * qh + t], __shfl(z, 8 * qh + t), p);
        p += __shfl_xor(p, 16);
        p += __shfl_xor(p, 32);
        z = fmaxf(p + b3[j3], 0.f);
    }
    {
        float t4 = w4[lane & 15] * z;
        t4 += __shfl_xor(t4, 1); t4 += __shfl_xor(t4, 2);
        t4 += __shfl_xor(t4, 4); t4 += __shfl_xor(t4, 8);
        float o = t4 + b4[0];
        if (lane == 0) out[s] = 1.f / (1.f + expf(-o));
    }
}

// ---------------------------------------------------------------------------
extern "C" void kernel_launch(void* const* d_in, const int* in_sizes, int n_in,
                              void* d_out, int out_size, void* d_ws, size_t ws_size,
                              hipStream_t stream)
{
    const float* x    = (const float*)d_in[0];
    const float* c1w  = (const float*)d_in[1];
    const float* c1b  = (const float*)d_in[2];
    const float* bn1g = (const float*)d_in[3];
    const float* bn1b = (const float*)d_in[4];
    const float* bn1m = (const float*)d_in[5];
    const float* bn1v = (const float*)d_in[6];
    const float* c2w  = (const float*)d_in[7];
    const float* c2b  = (const float*)d_in[8];
    const float* bn2g = (const float*)d_in[9];
    const float* bn2b = (const float*)d_in[10];
    const float* bn2m = (const float*)d_in[11];
    const float* bn2v = (const float*)d_in[12];
    const float* c3w  = (const float*)d_in[13];
    const float* c3b  = (const float*)d_in[14];
    const float* bn3g = (const float*)d_in[15];
    const float* bn3b = (const float*)d_in[16];
    const float* bn3m = (const float*)d_in[17];
    const float* bn3v = (const float*)d_in[18];
    const float* f1w  = (const float*)d_in[19];
    const float* f1b  = (const float*)d_in[20];
    const float* f2w  = (const float*)d_in[21];
    const float* f2b  = (const float*)d_in[22];
    const float* qw   = (const float*)d_in[23];
    const float* w1   = (const float*)d_in[24];
    const float* b1   = (const float*)d_in[25];
    const float* cg   = (const float*)d_in[26];
    const float* cb   = (const float*)d_in[27];
    const float* cm   = (const float*)d_in[28];
    const float* cv   = (const float*)d_in[29];
    const float* w2   = (const float*)d_in[30];
    const float* b2   = (const float*)d_in[31];
    const float* w3   = (const float*)d_in[32];
    const float* b3   = (const float*)d_in[33];
    const float* w4   = (const float*)d_in[34];
    const float* b4   = (const float*)d_in[35];

    unsigned short* ws = (unsigned short*)d_ws;
    unsigned short* pooled_bf = ws;                              // 8192*512 ush
    unsigned short* a1_bf     = pooled_bf + (size_t)BATCH * 512; // 8192*384 ush
    float*          a2        = (float*)(a1_bf + (size_t)BATCH * 384); // 8192*256 f32
    unsigned short* cpack     = (unsigned short*)(a2 + (size_t)BATCH * 256);
    unsigned short* fpack1    = cpack + CPACK_TOTAL;
    unsigned short* fpack2    = fpack1 + FC1_TOTAL;
    float*          angtab    = (float*)(fpack2 + FC2_TOTAL);

    prepack_kernel<<<(PREP_TOTAL + 255) / 256, 256, 0, stream>>>(
        c1w, c2w, c3w, f1w, f2w, qw, cpack, fpack1, fpack2, angtab);

    fused_cnn_mfma<<<BATCH, 256, 0, stream>>>(
        x, c1b, bn1g, bn1b, bn1m, bn1v,
        c2b, bn2g, bn2b, bn2m, bn2v,
        c3b, bn3g, bn3b, bn3m, bn3v, cpack, pooled_bf);

    dim3 g1(BATCH / 128, 384 / 64);
    fc_mfma<1><<<g1, 256, 0, stream>>>(pooled_bf, fpack1, f1b, a1_bf, 384, 512);

    dim3 g2(BATCH / 128, 256 / 64);
    fc_mfma<0><<<g2, 256, 0, stream>>>(a1_bf, fpack2, f2b, a2, 256, 384);

    qsim_tail_kernel<<<BATCH / 4, 256, 0, stream>>>(
        a2, angtab, w1, b1, cg, cb, cm, cv, w2, b2, w3, b3, w4, b4, (float*)d_out);
}

// Round 8
// 122.119 us; speedup vs baseline: 15.2941x; 1.1575x over previous
//
#include <hip/hip_runtime.h>
#include <hip/hip_bf16.h>
#include <math.h>

#define BATCH 8192

typedef __attribute__((ext_vector_type(8))) short bf16x8;
typedef __attribute__((ext_vector_type(4))) float f32x4;
typedef __attribute__((ext_vector_type(16))) float f32x16;

__device__ __forceinline__ unsigned short f2bf(float f) {
    unsigned int u = __builtin_bit_cast(unsigned int, f);
    u = (u + 0x7FFFu + ((u >> 16) & 1u)) >> 16;
    return (unsigned short)u;
}
__device__ __forceinline__ float bf2f(unsigned short h) {
    unsigned int u = ((unsigned int)h) << 16;
    return __builtin_bit_cast(float, u);
}
// HW packed convert (RNE), 1 VALU op for 2 values
__device__ __forceinline__ unsigned int cvtpk(float a, float b) {
    unsigned int r;
    asm("v_cvt_pk_bf16_f32 %0, %1, %2" : "=v"(r) : "v"(a), "v"(b));
    return r;
}
// bank-spreading swizzle at uint4 granularity (h1p only)
__device__ __forceinline__ int swz(int i) { return i ^ ((i >> 3) & 3); }

// ---- conv weight fragment pack (ushorts) ----
// W1: 4 frags [sel][hl] (lo kept in pack, unused): A operand, row=oc(0..7).
// W2: 6 frags [ky][hl] (lo unused). W3: 18 frags [ky][kx][hl] (lo unused).
#define W1OFF 0
#define W1FRAGS 4
#define W2OFF (W1OFF + W1FRAGS * 512)
#define W2FRAGS 6
#define W3OFF (W2OFF + W2FRAGS * 512)
#define W3FRAGS 18
#define CPACK_TOTAL (W3OFF + W3FRAGS * 512)
#define FC1_FRAGS (24 * 16 * 2)
#define FC2_FRAGS (16 * 12 * 2)
#define FC1_TOTAL (FC1_FRAGS * 512)
#define FC2_TOTAL (FC2_FRAGS * 512)
#define ANG_TOTAL 112
#define PREP_TOTAL (CPACK_TOTAL + FC1_TOTAL + FC2_TOTAL + ANG_TOTAL)

// ---------------------------------------------------------------------------
__global__ __launch_bounds__(256) void prepack_kernel(
    const float* __restrict__ c1w, const float* __restrict__ c2w,
    const float* __restrict__ c3w, const float* __restrict__ f1w,
    const float* __restrict__ f2w, const float* __restrict__ qw,
    unsigned short* __restrict__ cpack, unsigned short* __restrict__ fpack1,
    unsigned short* __restrict__ fpack2, float* __restrict__ angtab)
{
    int e = blockIdx.x * 256 + threadIdx.x;
    if (e >= PREP_TOTAL) return;

    if (e < CPACK_TOTAL) {
        int f = e >> 9, r = e & 511;
        int l = r >> 3, j = r & 7;
        float w = 0.f; int hl = 0;
        if (f < W1FRAGS) {
            int sel = f >> 1; hl = f & 1;
            int oc = l & 15;
            int k = 8 * (l >> 4) + j;
            int ky, kx;
            if (sel == 0) { ky = k >> 3; kx = k & 7; }
            else          { ky = 4;      kx = k; }
            if (kx < 5 && ky < 5 && oc < 8) w = c1w[oc * 25 + ky * 5 + kx];
        } else if (f < W1FRAGS + W2FRAGS) {
            int f2 = f - W1FRAGS;
            int ky = f2 >> 1; hl = f2 & 1;
            int k = 8 * (l >> 4) + j;
            int kx = k >> 3, ic = k & 7, oc = l & 15;
            if (kx < 3) w = c2w[((oc * 8 + ic) * 3 + ky) * 3 + kx];
        } else {
            int f3 = f - W1FRAGS - W2FRAGS;      // (ky*3+kx)*2+hl
            int ky = f3 / 6, kx = (f3 / 2) % 3; hl = f3 & 1;
            int oc = l & 31, ic = 8 * (l >> 5) + j;
            w = c3w[((oc * 16 + ic) * 3 + ky) * 3 + kx];
        }
        unsigned short hv = f2bf(w);
        unsigned short lv = f2bf(w - bf2f(hv));
        cpack[e] = hl ? lv : hv;
        return;
    }
    e -= CPACK_TOTAL;
    if (e < FC1_TOTAL) {
        int phi = e >> 9, r = e & 511;
        int l = r >> 3, j = r & 7;
        int hl = phi & 1, ks = (phi >> 1) & 15, nb = phi >> 5;
        int n = nb * 16 + (l & 15);
        int kg = ks * 32 + 8 * (l >> 4) + j;
        float w = f1w[n * 512 + kg];
        unsigned short hv = f2bf(w);
        unsigned short lv = f2bf(w - bf2f(hv));
        fpack1[e] = hl ? lv : hv;
        return;
    }
    e -= FC1_TOTAL;
    if (e < FC2_TOTAL) {
        int phi = e >> 9, r = e & 511;
        int l = r >> 3, j = r & 7;
        int hl = phi & 1, ks = (phi >> 1) % 12, nb = phi / 24;
        int n = nb * 16 + (l & 15);
        int kg = ks * 32 + 8 * (l >> 4) + j;
        float w = f2w[n * 384 + kg];
        unsigned short hv = f2bf(w);
        unsigned short lv = f2bf(w - bf2f(hv));
        fpack2[e] = hl ? lv : hv;
        return;
    }
    e -= FC2_TOTAL;
    {
        int a = e >> 1;
        float th = 0.5f * qw[a];
        angtab[e] = (e & 1) ? sinf(th) : cosf(th);
    }
}

// ---------------------------------------------------------------------------
// Fused CNN. One block (4 waves) per sample. 3 barriers.
// LDS: h1p [34*34 swz] uint4; sd = xp 68x40 dw | h2p planar [2][18*18] uint4.
// Convs use hi-bf16 weights only (lo dropped — bf16-activation rounding is
// already the same magnitude; 4 rounds measured absmax 0.0 at bf16 compare).
// ---------------------------------------------------------------------------
__global__ __launch_bounds__(256) void fused_cnn_mfma(
    const float* __restrict__ x,
    const float* __restrict__ c1b,
    const float* __restrict__ bn1g, const float* __restrict__ bn1b,
    const float* __restrict__ bn1m, const float* __restrict__ bn1v,
    const float* __restrict__ c2b,
    const float* __restrict__ bn2g, const float* __restrict__ bn2b,
    const float* __restrict__ bn2m, const float* __restrict__ bn2v,
    const float* __restrict__ c3b,
    const float* __restrict__ bn3g, const float* __restrict__ bn3b,
    const float* __restrict__ bn3m, const float* __restrict__ bn3v,
    const unsigned short* __restrict__ cpack,
    unsigned short* __restrict__ pooled_bf)
{
    __shared__ __align__(16) uint4 h1p4[1160];          // 34*34 px + pad
    __shared__ __align__(16) unsigned int sd[2720];     // xp / h2p planar 648 uint4

    uint4* sbuf4 = (uint4*)sd;

    const int tid = threadIdx.x;
    const int lane = tid & 63;
    const int wv = tid >> 6;
    const int n = blockIdx.x;
    const int lrow = lane & 15;
    const int lq = lane >> 4;         // 0..3

    // ---- P0: stage x interior (bf16) + zero xp pads + zero h1p ring ----
    {
        const float4* xv = (const float4*)(x + (size_t)n * 4096);
        #pragma unroll
        for (int i = 0; i < 4; ++i) {
            int idx = tid + 256 * i;
            float4 v = xv[idx];
            int px = idx * 4;
            int y = px >> 6, xc = px & 63;
            int d = (y + 2) * 40 + (xc >> 1) + 1;
            sd[d]     = cvtpk(v.x, v.y);
            sd[d + 1] = cvtpk(v.z, v.w);
        }
        if (tid < 68)       { int r = tid / 34, c = tid % 34; sd[r * 40 + c] = 0u; }
        else if (tid < 136) { int u = tid - 68; int r = 66 + u / 34, c = u % 34; sd[r * 40 + c] = 0u; }
        if (tid < 128) { int r = 2 + (tid & 63); sd[r * 40 + ((tid >> 6) ? 33 : 0)] = 0u; }
        if (tid < 132) {
            int p;
            if (tid < 34) p = tid;
            else if (tid < 68) p = 33 * 34 + (tid - 34);
            else { int r = 1 + ((tid - 68) & 31); int side = (tid - 68) >> 5; p = r * 34 + side * 33; }
            h1p4[swz(p)] = (uint4){0u, 0u, 0u, 0u};
        }
    }
    __syncthreads();   // B1

    // ---- conv1 (swapped, hi only): A=weights [oc][k], B=pixels. 2 MFMAs/t.
    {
        bf16x8 wf0 = __builtin_bit_cast(bf16x8, *(const uint4*)(cpack + W1OFF + lane * 8));
        bf16x8 wf2 = __builtin_bit_cast(bf16x8, *(const uint4*)(cpack + W1OFF + 2 * 512 + lane * 8));
        float s1v[4], sh1v[4];
        #pragma unroll
        for (int r = 0; r < 4; ++r) {
            int oc = (4 * lq + r) & 7;
            s1v[r] = bn1g[oc] * rsqrtf(bn1v[oc] + 1e-5f);
            sh1v[r] = (c1b[oc] - bn1m[oc]) * s1v[r] + bn1b[oc];
        }
        #pragma unroll 4
        for (int t = 0; t < 16; ++t) {
            int oy = wv * 8 + (t >> 1), h = t & 1;
            int a1 = (2 * oy + lq) * 40 + 16 * h + lrow;
            uint4 d1; d1.x = sd[a1]; d1.y = sd[a1 + 1]; d1.z = sd[a1 + 2]; d1.w = 0u;
            int a2 = (2 * oy + 4) * 40 + 16 * h + lrow;   // lq-invariant -> broadcast
            uint4 d2; d2.x = sd[a2]; d2.y = sd[a2 + 1]; d2.z = sd[a2 + 2]; d2.w = 0u;
            f32x4 acc = {0.f, 0.f, 0.f, 0.f};
            acc = __builtin_amdgcn_mfma_f32_16x16x32_bf16(wf0, __builtin_bit_cast(bf16x8, d1), acc, 0, 0, 0);
            acc = __builtin_amdgcn_mfma_f32_16x16x32_bf16(wf2, __builtin_bit_cast(bf16x8, d2), acc, 0, 0, 0);
            if (lq < 2) {
                unsigned int u0 = cvtpk(fmaxf(fmaf(acc[0], s1v[0], sh1v[0]), 0.f),
                                        fmaxf(fmaf(acc[1], s1v[1], sh1v[1]), 0.f));
                unsigned int u1 = cvtpk(fmaxf(fmaf(acc[2], s1v[2], sh1v[2]), 0.f),
                                        fmaxf(fmaf(acc[3], s1v[3], sh1v[3]), 0.f));
                int p = (oy + 1) * 34 + 16 * h + lrow + 1;
                uint2 wr; wr.x = u0; wr.y = u1;
                *(uint2*)((char*)h1p4 + swz(p) * 16 + 8 * lq) = wr;   // oc 4lq..4lq+3
            }
        }
    }
    __syncthreads();   // B2

    // ---- P2: zero h2p ring (planar) + conv2 (swapped, hi only) ----
    {
        if (tid < 136) {
            int pp = tid >> 1, plane = tid & 1;
            int p;
            if (pp < 18) p = pp;
            else if (pp < 36) p = 17 * 18 + (pp - 18);
            else { int r = 1 + ((pp - 36) & 15); int side = (pp - 36) >> 4; p = r * 18 + side * 17; }
            sbuf4[plane * 324 + p] = (uint4){0u, 0u, 0u, 0u};
        }
        bf16x8 w2f[3];
        #pragma unroll
        for (int ky = 0; ky < 3; ++ky)
            w2f[ky] = __builtin_bit_cast(bf16x8,
                *(const uint4*)(cpack + W2OFF + (ky * 2) * 512 + lane * 8));
        float s2v[4], sh2v[4];
        #pragma unroll
        for (int r = 0; r < 4; ++r) {
            int oc = 4 * lq + r;
            s2v[r] = bn2g[oc] * rsqrtf(bn2v[oc] + 1e-5f);
            sh2v[r] = (c2b[oc] - bn2m[oc]) * s2v[r] + bn2b[oc];
        }
        int lqe = (lq == 3) ? 0 : lq;      // kx=3 k-slots are zero-weight
        #pragma unroll
        for (int t = 0; t < 4; ++t) {
            int oy = 4 * wv + t;
            f32x4 acc = {0.f, 0.f, 0.f, 0.f};
            #pragma unroll
            for (int ky = 0; ky < 3; ++ky) {
                int iy = 2 * oy + ky;
                int p = iy * 34 + 2 * lrow + lqe;       // B: pix=lrow, kx=lq
                bf16x8 b = __builtin_bit_cast(bf16x8, h1p4[swz(p)]);
                acc = __builtin_amdgcn_mfma_f32_16x16x32_bf16(w2f[ky], b, acc, 0, 0, 0);
            }
            unsigned int u0 = cvtpk(fmaxf(fmaf(acc[0], s2v[0], sh2v[0]), 0.f),
                                    fmaxf(fmaf(acc[1], s2v[1], sh2v[1]), 0.f));
            unsigned int u1 = cvtpk(fmaxf(fmaf(acc[2], s2v[2], sh2v[2]), 0.f),
                                    fmaxf(fmaf(acc[3], s2v[3], sh2v[3]), 0.f));
            int p = (oy + 1) * 18 + lrow + 1;
            uint2 wr; wr.x = u0; wr.y = u1;
            // oc = 4lq+r -> plane = lq>>1, byte-in-pixel = 8*(lq&1)
            *(uint2*)((char*)sbuf4 + ((lq >> 1) * 324 + p) * 16 + 8 * (lq & 1)) = wr;
        }
    }
    __syncthreads();   // B3

    // ---- conv3: 16->32ch 3x3 s1 p1 (32x32x16, hi only) + BN/ReLU + pool ----
    {
        f32x16 accA = {0.f}, accB = {0.f};
        const int row = lane & 31;
        const int khalf = lane >> 5;
        const int kbase = khalf * 324;
        #pragma unroll
        for (int ky = 0; ky < 3; ++ky)
            #pragma unroll
            for (int kx = 0; kx < 3; ++kx) {
                int fb = (ky * 3 + kx) * 2;
                bf16x8 bh = __builtin_bit_cast(bf16x8, *(const uint4*)(cpack + W3OFF + fb * 512 + lane * 8));
                {
                    int pix = (4 * wv + 0 + (row >> 4) + ky) * 18 + (row & 15) + kx;
                    bf16x8 a = __builtin_bit_cast(bf16x8, sbuf4[kbase + pix]);
                    accA = __builtin_amdgcn_mfma_f32_32x32x16_bf16(a, bh, accA, 0, 0, 0);
                }
                {
                    int pix = (4 * wv + 2 + (row >> 4) + ky) * 18 + (row & 15) + kx;
                    bf16x8 a = __builtin_bit_cast(bf16x8, sbuf4[kbase + pix]);
                    accB = __builtin_amdgcn_mfma_f32_32x32x16_bf16(a, bh, accB, 0, 0, 0);
                }
            }
        int oc = lane & 31;
        float s3 = bn3g[oc] * rsqrtf(bn3v[oc] + 1e-5f);
        float sh3 = (c3b[oc] - bn3m[oc]) * s3 + bn3b[oc];
        float pool0 = 0.f, pool1 = 0.f;
        #pragma unroll
        for (int r = 0; r < 16; ++r) {
            float va = fmaxf(fmaf(accA[r], s3, sh3), 0.f);
            float vb = fmaxf(fmaf(accB[r], s3, sh3), 0.f);
            if (((r >> 2) & 1) == 0) { pool0 += va + vb; } else { pool1 += va + vb; }
        }
        int base = n * 512 + oc * 16 + wv * 4 + khalf;
        pooled_bf[base]     = (unsigned short)cvtpk(pool0 * (1.f / 16.f), 0.f);
        pooled_bf[base + 2] = (unsigned short)cvtpk(pool1 * (1.f / 16.f), 0.f);
    }
}

// ---------------------------------------------------------------------------
// FC GEMM (bf16 MFMA, hi/lo): out = relu(A @ W^T + bias). 128x64, BK=64.
// ---------------------------------------------------------------------------
template <int OUT_BF16>
__global__ __launch_bounds__(256) void fc_mfma(
    const unsigned short* __restrict__ Abf,
    const unsigned short* __restrict__ wfrag,
    const float* __restrict__ bias, void* __restrict__ out,
    int N, int K)
{
    __shared__ __align__(16) unsigned short As[8192];
    const int tid = threadIdx.x;
    const int lane = tid & 63;
    const int wv = tid >> 6;
    const int wm = wv >> 1, wn = wv & 1;
    const int bm = blockIdx.x * 128;
    const int bn = blockIdx.y * 64;
    const int lq = lane >> 4;
    const int lr = lane & 15;
    const int KS = K >> 5;

    f32x4 acc[4][2];
    #pragma unroll
    for (int i = 0; i < 4; ++i) { acc[i][0] = (f32x4){0,0,0,0}; acc[i][1] = (f32x4){0,0,0,0}; }

    for (int k0 = 0; k0 < K; k0 += 64) {
        #pragma unroll
        for (int i = 0; i < 4; ++i) {
            int q = tid * 4 + i;
            int row = q >> 3, kc = q & 7;
            uint4 v = *(const uint4*)(Abf + (size_t)(bm + row) * K + k0 + 8 * kc);
            int byte = (row * 128 + 16 * kc) ^ ((row & 7) << 4);
            *(uint4*)((char*)As + byte) = v;
        }
        __syncthreads();
        #pragma unroll
        for (int kk = 0; kk < 2; ++kk) {
            bf16x8 af[4];
            #pragma unroll
            for (int mf = 0; mf < 4; ++mf) {
                int ml = wm * 64 + mf * 16 + lr;
                int byte = (ml * 128 + 64 * kk + 16 * lq) ^ ((ml & 7) << 4);
                af[mf] = __builtin_bit_cast(bf16x8, *(const uint4*)((char*)As + byte));
            }
            int ks = (k0 >> 5) + kk;
            #pragma unroll
            for (int nf = 0; nf < 2; ++nf) {
                int nb = (bn >> 4) + wn * 2 + nf;
                const unsigned short* fb = wfrag + ((size_t)(nb * KS + ks) * 2) * 512 + lane * 8;
                bf16x8 bh = __builtin_bit_cast(bf16x8, *(const uint4*)fb);
                bf16x8 bl = __builtin_bit_cast(bf16x8, *(const uint4*)(fb + 512));
                #pragma unroll
                for (int mf = 0; mf < 4; ++mf) {
                    acc[mf][nf] = __builtin_amdgcn_mfma_f32_16x16x32_bf16(af[mf], bh, acc[mf][nf], 0, 0, 0);
                    acc[mf][nf] = __builtin_amdgcn_mfma_f32_16x16x32_bf16(af[mf], bl, acc[mf][nf], 0, 0, 0);
                }
            }
        }
        __syncthreads();
    }

    #pragma unroll
    for (int nf = 0; nf < 2; ++nf) {
        int nn = bn + wn * 32 + nf * 16 + lr;
        float bv = bias[nn];
        #pragma unroll
        for (int mf = 0; mf < 4; ++mf)
            #pragma unroll
            for (int r = 0; r < 4; ++r) {
                int m = bm + wm * 64 + mf * 16 + 4 * lq + r;
                float v = fmaxf(acc[mf][nf][r] + bv, 0.f);
                if (OUT_BF16) ((unsigned short*)out)[(size_t)m * N + nn] = (unsigned short)cvtpk(v, 0.f);
                else          ((float*)out)[(size_t)m * N + nn] = v;
            }
    }
}

// ---------------------------------------------------------------------------
// L2-norm + 8-qubit/7-layer qsim + fused tail MLP. One wave per sample.
// ---------------------------------------------------------------------------
__global__ __launch_bounds__(256) void qsim_tail_kernel(
    const float* __restrict__ feats, const float* __restrict__ angtab,
    const float* __restrict__ w1, const float* __restrict__ b1,
    const float* __restrict__ cg, const float* __restrict__ cb,
    const float* __restrict__ cm, const float* __restrict__ cv,
    const float* __restrict__ w2, const float* __restrict__ b2,
    const float* __restrict__ w3, const float* __restrict__ b3,
    const float* __restrict__ w4, const float* __restrict__ b4,
    float* __restrict__ out)
{
    const int lane = threadIdx.x & 63;
    const int wid = threadIdx.x >> 6;
    const int s = blockIdx.x * 4 + wid;

    float4 v = *(const float4*)(feats + (size_t)s * 256 + lane * 4);
    float a0 = v.x, a1 = v.y, a2 = v.z, a3 = v.w;

    float ss = a0 * a0 + a1 * a1 + a2 * a2 + a3 * a3;
    #pragma unroll
    for (int m = 32; m; m >>= 1) ss += __shfl_xor(ss, m);
    float inv = 1.f / fmaxf(sqrtf(ss), 1e-12f);
    a0 *= inv; a1 *= inv; a2 *= inv; a3 *= inv;

    const int csrc = lane ^ ((lane >> 1) & 31);

    for (int l = 0; l < 7; ++l) {
        #pragma unroll
        for (int q = 0; q < 6; ++q) {
            float cs = angtab[(l * 8 + q) * 2], sn = angtab[(l * 8 + q) * 2 + 1];
            int mask = 32 >> q;
            float sg = (lane & mask) ? sn : -sn;
            float b0 = __shfl_xor(a0, mask), b1v = __shfl_xor(a1, mask);
            float b2v = __shfl_xor(a2, mask), b3v = __shfl_xor(a3, mask);
            a0 = fmaf(sg, b0, cs * a0); a1 = fmaf(sg, b1v, cs * a1);
            a2 = fmaf(sg, b2v, cs * a2); a3 = fmaf(sg, b3v, cs * a3);
        }
        {
            float cs = angtab[(l * 8 + 6) * 2], sn = angtab[(l * 8 + 6) * 2 + 1];
            float n0 = cs * a0 - sn * a2, n2 = fmaf(sn, a0, cs * a2);
            float n1 = cs * a1 - sn * a3, n3 = fmaf(sn, a1, cs * a3);
            a0 = n0; a1 = n1; a2 = n2; a3 = n3;
        }
        {
            float cs = angtab[(l * 8 + 7) * 2], sn = angtab[(l * 8 + 7) * 2 + 1];
            float n0 = cs * a0 - sn * a1, n1 = fmaf(sn, a0, cs * a1);
            float n2 = cs * a2 - sn * a3, n3 = fmaf(sn, a2, cs * a3);
            a0 = n0; a1 = n1; a2 = n2; a3 = n3;
        }
        a0 = __shfl(a0, csrc); a1 = __shfl(a1, csrc);
        a2 = __shfl(a2, csrc); a3 = __shfl(a3, csrc);
        {
            bool f = (lane & 1);
            float n0 = f ? a2 : a0, n2 = f ? a0 : a2;
            float n1 = f ? a3 : a1, n3 = f ? a1 : a3;
            a0 = n0; a1 = n1; a2 = n2; a3 = n3;
        }
        { float t = a2; a2 = a3; a3 = t; }
    }

    float part = a0 * a0 + a1 * a1 + a2 * a2 + a3 * a3;
    part = (lane & 32) ? -part : part;
    #pragma unroll
    for (int m = 32; m; m >>= 1) part += __shfl_xor(part, m);
    float q = part;

    float z = fmaxf(fmaf(q, w1[lane], b1[lane]), 0.f);
    z = fmaf(z - cm[lane], cg[lane] * rsqrtf(cv[lane] + 1e-5f), cb[lane]);
    {
        int j = lane & 31, hb = lane & 32;
        float acc = 0.f;
        #pragma unroll
        for (int t = 0; t < 32; ++t)
            acc = fmaf(w2[j * 64 + hb + t], __shfl(z, hb + t), acc);
        acc += __shfl_xor(acc, 32);
        z = fmaxf(acc + b2[j], 0.f);
    }
    {
        int j3 = lane & 15, qh = (lane >> 4) & 3;
        float p = 0.f;
        #pragma unroll
        for (int t = 0; t < 8; ++t)
            p = fmaf(w3[j3 * 32 + 8 * qh + t], __shfl(z, 8 * qh + t), p);
        p += __shfl_xor(p, 16);
        p += __shfl_xor(p, 32);
        z = fmaxf(p + b3[j3], 0.f);
    }
    {
        float t4 = w4[lane & 15] * z;
        t4 += __shfl_xor(t4, 1); t4 += __shfl_xor(t4, 2);
        t4 += __shfl_xor(t4, 4); t4 += __shfl_xor(t4, 8);
        float o = t4 + b4[0];
        if (lane == 0) out[s] = 1.f / (1.f + expf(-o));
    }
}

// ---------------------------------------------------------------------------
extern "C" void kernel_launch(void* const* d_in, const int* in_sizes, int n_in,
                              void* d_out, int out_size, void* d_ws, size_t ws_size,
                              hipStream_t stream)
{
    const float* x    = (const float*)d_in[0];
    const float* c1w  = (const float*)d_in[1];
    const float* c1b  = (const float*)d_in[2];
    const float* bn1g = (const float*)d_in[3];
    const float* bn1b = (const float*)d_in[4];
    const float* bn1m = (const float*)d_in[5];
    const float* bn1v = (const float*)d_in[6];
    const float* c2w  = (const float*)d_in[7];
    const float* c2b  = (const float*)d_in[8];
    const float* bn2g = (const float*)d_in[9];
    const float* bn2b = (const float*)d_in[10];
    const float* bn2m = (const float*)d_in[11];
    const float* bn2v = (const float*)d_in[12];
    const float* c3w  = (const float*)d_in[13];
    const float* c3b  = (const float*)d_in[14];
    const float* bn3g = (const float*)d_in[15];
    const float* bn3b = (const float*)d_in[16];
    const float* bn3m = (const float*)d_in[17];
    const float* bn3v = (const float*)d_in[18];
    const float* f1w  = (const float*)d_in[19];
    const float* f1b  = (const float*)d_in[20];
    const float* f2w  = (const float*)d_in[21];
    const float* f2b  = (const float*)d_in[22];
    const float* qw   = (const float*)d_in[23];
    const float* w1   = (const float*)d_in[24];
    const float* b1   = (const float*)d_in[25];
    const float* cg   = (const float*)d_in[26];
    const float* cb   = (const float*)d_in[27];
    const float* cm   = (const float*)d_in[28];
    const float* cv   = (const float*)d_in[29];
    const float* w2   = (const float*)d_in[30];
    const float* b2   = (const float*)d_in[31];
    const float* w3   = (const float*)d_in[32];
    const float* b3   = (const float*)d_in[33];
    const float* w4   = (const float*)d_in[34];
    const float* b4   = (const float*)d_in[35];

    unsigned short* ws = (unsigned short*)d_ws;
    unsigned short* pooled_bf = ws;                              // 8192*512 ush
    unsigned short* a1_bf     = pooled_bf + (size_t)BATCH * 512; // 8192*384 ush
    float*          a2        = (float*)(a1_bf + (size_t)BATCH * 384); // 8192*256 f32
    unsigned short* cpack     = (unsigned short*)(a2 + (size_t)BATCH * 256);
    unsigned short* fpack1    = cpack + CPACK_TOTAL;
    unsigned short* fpack2    = fpack1 + FC1_TOTAL;
    float*          angtab    = (float*)(fpack2 + FC2_TOTAL);

    prepack_kernel<<<(PREP_TOTAL + 255) / 256, 256, 0, stream>>>(
        c1w, c2w, c3w, f1w, f2w, qw, cpack, fpack1, fpack2, angtab);

    fused_cnn_mfma<<<BATCH, 256, 0, stream>>>(
        x, c1b, bn1g, bn1b, bn1m, bn1v,
        c2b, bn2g, bn2b, bn2m, bn2v,
        c3b, bn3g, bn3b, bn3m, bn3v, cpack, pooled_bf);

    dim3 g1(BATCH / 128, 384 / 64);
    fc_mfma<1><<<g1, 256, 0, stream>>>(pooled_bf, fpack1, f1b, a1_bf, 384, 512);

    dim3 g2(BATCH / 128, 256 / 64);
    fc_mfma<0><<<g2, 256, 0, stream>>>(a1_bf, fpack2, f2b, a2, 256, 384);

    qsim_tail_kernel<<<BATCH / 4, 256, 0, stream>>>(
        a2, angtab, w1, b1, cg, cb, cm, cv, w2, b2, w3, b3, w4, b4, (float*)d_out);
}